// Round 3
// baseline (1459.130 us; speedup 1.0000x reference)
//
#include <hip/hip_runtime.h>
#include <hip/hip_bf16.h>

#define NTX    100000
#define NADDR  200000
#define NEDGE  400000
#define FTX    165
#define HDIM   256
#define NEG_SLOPE 0.2f
#define LN_EPS 1e-5f
#define GTPB   2      // row-tiles per block in gemm_mfma

typedef __hip_bfloat16 bf16;
typedef __attribute__((ext_vector_type(8))) short short8;   // 8 bf16 = 4 VGPRs
typedef __attribute__((ext_vector_type(4))) float floatx4;

__device__ __forceinline__ float to_f(float x) { return x; }
__device__ __forceinline__ float to_f(bf16 x) { return __bfloat162float(x); }
__device__ __forceinline__ void from_f(float x, float& o) { o = x; }
__device__ __forceinline__ void from_f(float x, bf16& o) { o = __float2bfloat16(x); }

__device__ __forceinline__ float b2f(short s) {
    unsigned u = ((unsigned)(unsigned short)s) << 16;
    return __uint_as_float(u);
}
__device__ __forceinline__ short f2b(float x) {
    bf16 t = __float2bfloat16(x);
    return *reinterpret_cast<short*>(&t);
}

__device__ __forceinline__ float4 load_bf16x4(const bf16* p) {
    const __hip_bfloat162* q = (const __hip_bfloat162*)p;
    __hip_bfloat162 v0 = q[0], v1 = q[1];
    return make_float4(__bfloat162float(v0.x), __bfloat162float(v0.y),
                       __bfloat162float(v1.x), __bfloat162float(v1.y));
}
__device__ __forceinline__ void store_bf16x4(bf16* p, float4 v) {
    __hip_bfloat162* q = (__hip_bfloat162*)p;
    __hip_bfloat162 t0, t1;
    t0.x = __float2bfloat16(v.x); t0.y = __float2bfloat16(v.y);
    t1.x = __float2bfloat16(v.z); t1.y = __float2bfloat16(v.w);
    q[0] = t0; q[1] = t1;
}

// async global->LDS, 16B per lane. LDS dest = wave-uniform base + lane*16.
__device__ __forceinline__ void gload_lds16(const bf16* g, bf16* l) {
    __builtin_amdgcn_global_load_lds(
        (const __attribute__((address_space(1))) void*)g,
        (__attribute__((address_space(3))) void*)l, 16, 0, 0);
}

// ---------------------------------------------------------------------------
// fp32 SIMD GEMM (in-projections only). 64x64 tile, BK=16, 4x4 microtile.
// ---------------------------------------------------------------------------
template<typename TA, typename TC>
__global__ __launch_bounds__(256) void gemm_t(
    const TA* __restrict__ A, const float* __restrict__ B,
    const float* __restrict__ bias, TC* __restrict__ C,
    int M, int N, int K)
{
    __shared__ float As[16][64];
    __shared__ float Bs[16][64];
    const int t = threadIdx.x;
    const int row0 = blockIdx.x * 64;
    const int col0 = blockIdx.y * 64;
    const int tm = t >> 4, tn = t & 15;
    float acc[4][4] = {};
    for (int k0 = 0; k0 < K; k0 += 16) {
#pragma unroll
        for (int i = 0; i < 4; ++i) {
            int idx = t + 256 * i;
            int m = idx >> 4, kk = idx & 15;
            int r = row0 + m, c = k0 + kk;
            As[kk][m] = (r < M && c < K) ? to_f(A[(size_t)r * K + c]) : 0.f;
        }
#pragma unroll
        for (int i = 0; i < 4; ++i) {
            int idx = t + 256 * i;
            int kk = idx >> 6, n = idx & 63;
            int r = k0 + kk;
            Bs[kk][n] = (r < K) ? B[(size_t)r * N + col0 + n] : 0.f;
        }
        __syncthreads();
#pragma unroll
        for (int kk = 0; kk < 16; ++kk) {
            const float4 a4 = *(const float4*)&As[kk][tm * 4];
            const float4 b4 = *(const float4*)&Bs[kk][tn * 4];
            float a_[4] = {a4.x, a4.y, a4.z, a4.w};
            float b_[4] = {b4.x, b4.y, b4.z, b4.w};
#pragma unroll
            for (int i = 0; i < 4; ++i)
#pragma unroll
                for (int j = 0; j < 4; ++j)
                    acc[i][j] += a_[i] * b_[j];
        }
        __syncthreads();
    }
    float4 bv = make_float4(0.f, 0.f, 0.f, 0.f);
    if (bias) bv = *(const float4*)&bias[col0 + tn * 4];
#pragma unroll
    for (int i = 0; i < 4; ++i) {
        int r = row0 + tm * 4 + i;
        if (r < M) {
            TC* cp = &C[(size_t)r * N + col0 + tn * 4];
            from_f(acc[i][0] + bv.x, cp[0]);
            from_f(acc[i][1] + bv.y, cp[1]);
            from_f(acc[i][2] + bv.z, cp[2]);
            from_f(acc[i][3] + bv.w, cp[3]);
        }
    }
}

// ---------------------------------------------------------------------------
// Wt[n,k] = bf16(W[k,n])  (one-time weight transpose+convert)
// ---------------------------------------------------------------------------
__global__ void transpose_w(const float* __restrict__ W, bf16* __restrict__ Wt,
                            int K, int N)
{
    int idx = blockIdx.x * blockDim.x + threadIdx.x;
    if (idx >= K * N) return;
    int k = idx / N, n = idx - k * N;
    Wt[(size_t)n * K + k] = __float2bfloat16(W[idx]);
}

// ---------------------------------------------------------------------------
// MFMA bf16 GEMM: C[M,N] = A[M,K] @ Wt[N,K]^T (+bias).
// 128x128 tile, BK=32, 4 waves. 2-phase double-buffered pipeline (T3/T4
// minimum recipe): STAGE(next) issued BEFORE compute(cur); one combined
// {s_waitcnt vmcnt(0); s_barrier} per K-step so next-tile HBM latency hides
// under ds_read+MFMA(+C-write). Each block walks GTPB row-tiles (same col),
// lengthening the pipeline and amortizing the prologue drain.
// Swizzle: chunk-XOR on global SOURCE and ds_read address (involution).
// ---------------------------------------------------------------------------
template<typename TC>
__global__ __launch_bounds__(256) void gemm_mfma(
    const bf16* __restrict__ A, const bf16* __restrict__ Wt,
    const float* __restrict__ bias, TC* __restrict__ C,
    int M, int N, int K)
{
    __shared__ __align__(16) bf16 As[2][128 * 32];
    __shared__ __align__(16) bf16 Bs[2][128 * 32];
    const int t = threadIdx.x;
    const int wv = t >> 6, lane = t & 63;
    const int l15 = lane & 15, quad = lane >> 4;

    // bijective XCD-chunked block swizzle (m204)
    const int nbk = gridDim.x;
    const int orig = blockIdx.x;
    const int q = nbk >> 3, rrm = nbk & 7;
    const int xcd = orig & 7, jj = orig >> 3;
    const int wgid = (xcd < rrm ? xcd * (q + 1) : rrm * (q + 1) + (xcd - rrm) * q) + jj;
    const int ncol = N >> 7;
    const int chunk = wgid / ncol, bcol = wgid - chunk * ncol;
    const int col0 = bcol * 128;
    const int wrow = (wv >> 1) * 64, wcol = (wv & 1) * 64;

    const int nrow = (M + 127) >> 7;
    const int tile0 = chunk * GTPB;
    const int ntile = min(GTPB, nrow - tile0);
    const int KT = K >> 5;
    const int S = ntile * KT;

    // per-thread staging geometry: idx = t + 256*i covers 512 slots of 16B
    int rr_[2], ofs_[2], lds_[2];
#pragma unroll
    for (int i = 0; i < 2; ++i) {
        int idx = t + 256 * i;
        int r = idx >> 2, ch = idx & 3;
        int chs = ch ^ ((r >> 1) & 3);          // source-side swizzle
        rr_[i] = r;
        ofs_[i] = chs * 8;
        lds_[i] = (idx >> 6) * 512;             // wave-uniform base slot
    }

    // ds_read fragment offsets (loop-invariant), read-side swizzle
    int offA[4], offB[4];
#pragma unroll
    for (int rb = 0; rb < 4; ++rb) {
        int ra = wrow + rb * 16 + l15;
        offA[rb] = ra * 32 + ((quad ^ ((ra >> 1) & 3)) * 8);
        int rc = wcol + rb * 16 + l15;
        offB[rb] = rc * 32 + ((quad ^ ((rc >> 1) & 3)) * 8);
    }

    auto stage = [&](int buf, int tt, int ks) {
        const int row0 = (tile0 + tt) << 7;
        const int k0 = ks << 5;
#pragma unroll
        for (int i = 0; i < 2; ++i) {
            int r = row0 + rr_[i];
            if (r < M)
                gload_lds16(A + (size_t)r * K + k0 + ofs_[i], &As[buf][lds_[i]]);
            gload_lds16(Wt + (size_t)(col0 + rr_[i]) * K + k0 + ofs_[i],
                        &Bs[buf][lds_[i]]);
        }
    };

    floatx4 acc[4][4] = {};

    int buf = 0, tt = 0, ks = 0;
    stage(0, 0, 0);
    asm volatile("s_waitcnt vmcnt(0)\n\ts_barrier" ::: "memory");
    __builtin_amdgcn_sched_barrier(0);

    for (int s = 0; s < S; ++s) {
        int nks = ks + 1, ntt = tt;
        if (nks == KT) { nks = 0; ntt = tt + 1; }
        if (s + 1 < S) stage(buf ^ 1, ntt, nks);   // prefetch next K-step

        short8 af[4], bfr[4];
#pragma unroll
        for (int rb = 0; rb < 4; ++rb) af[rb] = *(const short8*)&As[buf][offA[rb]];
#pragma unroll
        for (int nbb = 0; nbb < 4; ++nbb) bfr[nbb] = *(const short8*)&Bs[buf][offB[nbb]];
#pragma unroll
        for (int rb = 0; rb < 4; ++rb)
#pragma unroll
            for (int nbb = 0; nbb < 4; ++nbb)
                acc[rb][nbb] = __builtin_amdgcn_mfma_f32_16x16x32_bf16(
                    af[rb], bfr[nbb], acc[rb][nbb], 0, 0, 0);

        if (ks == KT - 1) {                        // tile finished: epilogue
            const int row0 = (tile0 + tt) << 7;
#pragma unroll
            for (int rb = 0; rb < 4; ++rb)
#pragma unroll
                for (int nbb = 0; nbb < 4; ++nbb) {
                    int col = col0 + wcol + nbb * 16 + l15;
                    float bv = bias ? bias[col] : 0.f;
#pragma unroll
                    for (int r = 0; r < 4; ++r) {
                        int row = row0 + wrow + rb * 16 + quad * 4 + r;
                        if (row < M)
                            from_f(acc[rb][nbb][r] + bv, C[(size_t)row * N + col]);
                    }
                    acc[rb][nbb] = floatx4{0.f, 0.f, 0.f, 0.f};
                }
        }

        asm volatile("s_waitcnt vmcnt(0)\n\ts_barrier" ::: "memory");
        __builtin_amdgcn_sched_barrier(0);
        buf ^= 1; tt = ntt; ks = nks;
    }
}

// ---------------------------------------------------------------------------
// Vd[k,h] = sum_j W[k, h*64+j] * a_d[h,j]
// ---------------------------------------------------------------------------
__global__ void build_vd(const float* __restrict__ W, const float* __restrict__ a_d,
                         float* __restrict__ Vd, int K)
{
    int idx = blockIdx.x * blockDim.x + threadIdx.x;  // k*4+h
    if (idx >= K * 4) return;
    int k = idx >> 2, h = idx & 3;
    float d = 0.f;
    for (int j = 0; j < 64; ++j)
        d += W[(size_t)k * HDIM + h * 64 + j] * a_d[h * 64 + j];
    Vd[idx] = d;
}

// ---------------------------------------------------------------------------
// al_dst[n,h] = sum_k X[n,k] * V[k,h].  Wave per row, bf16x4 loads.
// ---------------------------------------------------------------------------
__global__ __launch_bounds__(256) void attn_dst(
    const bf16* __restrict__ X, const float* __restrict__ V,
    float* __restrict__ out, int M, int K)
{
    int n = (blockIdx.x * 256 + threadIdx.x) >> 6;
    int lane = threadIdx.x & 63;
    if (n >= M) return;
    const bf16* xr = X + (size_t)n * K;
    float a0 = 0.f, a1 = 0.f, a2 = 0.f, a3 = 0.f;
    for (int k0 = lane * 4; k0 < K; k0 += 256) {
        float4 x = load_bf16x4(xr + k0);
        float xv[4] = {x.x, x.y, x.z, x.w};
#pragma unroll
        for (int j = 0; j < 4; ++j) {
            const float4 v = *(const float4*)&V[(k0 + j) * 4];
            a0 += xv[j] * v.x; a1 += xv[j] * v.y;
            a2 += xv[j] * v.z; a3 += xv[j] * v.w;
        }
    }
#pragma unroll
    for (int off = 32; off; off >>= 1) {
        a0 += __shfl_xor(a0, off); a1 += __shfl_xor(a1, off);
        a2 += __shfl_xor(a2, off); a3 += __shfl_xor(a3, off);
    }
    if (lane == 0) {
        out[(size_t)n * 4 + 0] = a0; out[(size_t)n * 4 + 1] = a1;
        out[(size_t)n * 4 + 2] = a2; out[(size_t)n * 4 + 3] = a3;
    }
}

// ---------------------------------------------------------------------------
// al_src[n,h] = sum_j hs[n, h*64+j] * a_s[h,j].  Wave per row (hs 256-wide).
// ---------------------------------------------------------------------------
__global__ __launch_bounds__(256) void attn_src(
    const bf16* __restrict__ hs, const float* __restrict__ a_s,
    float* __restrict__ out, int M)
{
    int n = (blockIdx.x * 256 + threadIdx.x) >> 6;
    int lane = threadIdx.x & 63;
    if (n >= M) return;
    float4 v = load_bf16x4(hs + (size_t)n * HDIM + lane * 4);
    float4 a = *(const float4*)&a_s[lane * 4];
    float s = v.x * a.x + v.y * a.y + v.z * a.z + v.w * a.w;
#pragma unroll
    for (int off = 1; off < 16; off <<= 1) s += __shfl_xor(s, off);
    if ((lane & 15) == 0) out[(size_t)n * 4 + (lane >> 4)] = s;
}

// ---------------------------------------------------------------------------
// CSR build: histogram, 3-phase exclusive scan, scatter (writes csr_src/dst).
// ---------------------------------------------------------------------------
__global__ void k_hist(const int* __restrict__ dst, int* __restrict__ deg, int E)
{
    int e = blockIdx.x * blockDim.x + threadIdx.x;
    if (e < E) atomicAdd(&deg[dst[e]], 1);
}

__global__ void scan_partial(const int* __restrict__ deg, int* __restrict__ bsum, int N)
{
    __shared__ int lds[256];
    int base = blockIdx.x * 1024, t = threadIdx.x;
    int s = 0;
#pragma unroll
    for (int i = 0; i < 4; ++i) {
        int idx = base + t * 4 + i;
        if (idx < N) s += deg[idx];
    }
    lds[t] = s; __syncthreads();
    for (int off = 128; off; off >>= 1) {
        if (t < off) lds[t] += lds[t + off];
        __syncthreads();
    }
    if (t == 0) bsum[blockIdx.x] = lds[0];
}

__global__ void scan_bsum(int* __restrict__ bsum, int NB, int* __restrict__ rp, int N, int E)
{
    if (threadIdx.x == 0 && blockIdx.x == 0) {
        int acc = 0;
        for (int b = 0; b < NB; ++b) { int v = bsum[b]; bsum[b] = acc; acc += v; }
        rp[N] = E;
    }
}

__global__ void scan_write(const int* __restrict__ deg, const int* __restrict__ bsum,
                           int* __restrict__ rp, int N)
{
    __shared__ int lds[256];
    int base = blockIdx.x * 1024, t = threadIdx.x;
    int v[4]; int s = 0;
#pragma unroll
    for (int i = 0; i < 4; ++i) {
        int idx = base + t * 4 + i;
        v[i] = (idx < N) ? deg[idx] : 0;
        s += v[i];
    }
    lds[t] = s; __syncthreads();
    for (int off = 1; off < 256; off <<= 1) {
        int x = (t >= off) ? lds[t - off] : 0;
        __syncthreads();
        lds[t] += x;
        __syncthreads();
    }
    int excl = lds[t] - s + bsum[blockIdx.x];
#pragma unroll
    for (int i = 0; i < 4; ++i) {
        int idx = base + t * 4 + i;
        if (idx < N) rp[idx] = excl;
        excl += v[i];
    }
}

__global__ void k_scatter(const int* __restrict__ src, const int* __restrict__ dst,
                          const int* __restrict__ rp, int* __restrict__ cur,
                          int* __restrict__ csr_src, int* __restrict__ csr_dst, int E)
{
    int e = blockIdx.x * blockDim.x + threadIdx.x;
    if (e >= E) return;
    int d = dst[e];
    int pos = atomicAdd(&cur[d], 1);
    int p = rp[d] + pos;
    csr_src[p] = src[e];
    csr_dst[p] = d;
}

// ---------------------------------------------------------------------------
// Edge-parallel: ex_csr[i][h] = exp(leaky(al_src[csr_src[i]][h] + al_dst[csr_dst[i]][h]))
// ---------------------------------------------------------------------------
__global__ void edge_ex(const int* __restrict__ csr_src, const int* __restrict__ csr_dst,
                        const float* __restrict__ al_src, const float* __restrict__ al_dst,
                        float* __restrict__ ex_csr, int E)
{
    int i = blockIdx.x * blockDim.x + threadIdx.x;
    if (i >= E) return;
    int s = csr_src[i], d = csr_dst[i];
    float4 as4 = *(const float4*)&al_src[(size_t)s * 4];
    float4 ad4 = *(const float4*)&al_dst[(size_t)d * 4];
    float l[4] = {as4.x + ad4.x, as4.y + ad4.y, as4.z + ad4.z, as4.w + ad4.w};
    float4 o;
    float* op = (float*)&o;
#pragma unroll
    for (int h = 0; h < 4; ++h) {
        float v = l[h] >= 0.f ? l[h] : NEG_SLOPE * l[h];
        op[h] = __expf(v);
    }
    *(float4*)&ex_csr[(size_t)i * 4] = o;
}

// ---------------------------------------------------------------------------
// Fused per-dst-node: softmax-weighted gather (CSR, precomputed ex) + bias
// + LayerNorm (+residual) + ELU -> h_out (bf16). 2 nodes/wave, 16B gathers.
// ---------------------------------------------------------------------------
__global__ __launch_bounds__(256) void aggregate_ln_elu(
    const int* __restrict__ rp, const int* __restrict__ csr_src,
    const float* __restrict__ ex_csr, const bf16* __restrict__ hs,
    const float* __restrict__ bias, const float* __restrict__ g,
    const float* __restrict__ b,
    const bf16* __restrict__ res, bf16* __restrict__ h_out, int n_dst)
{
    const int wvg  = (blockIdx.x * 256 + threadIdx.x) >> 6;  // global wave id
    const int lane = threadIdx.x & 63;
    const int half = lane >> 5;           // which node of the pair
    const int l32  = lane & 31;           // lane within node
    const int d    = wvg * 2 + half;
    if (wvg * 2 >= n_dst) return;
    const bool valid = d < n_dst;
    const int head = l32 >> 3;            // 8 lanes per head

    int beg = 0, end = 0;
    if (valid) { beg = rp[d]; end = rp[d + 1]; }

    float acc[8] = {};
    float den = 0.f;
    int i = beg;
    for (; i + 2 <= end; i += 2) {
        int s0 = csr_src[i], s1 = csr_src[i + 1];
        float e0 = ex_csr[(size_t)i * 4 + head];
        float e1 = ex_csr[(size_t)(i + 1) * 4 + head];
        short8 v0 = *(const short8*)&hs[(size_t)s0 * HDIM + l32 * 8];
        short8 v1 = *(const short8*)&hs[(size_t)s1 * HDIM + l32 * 8];
        den += e0 + e1;
#pragma unroll
        for (int j = 0; j < 8; ++j)
            acc[j] += e0 * b2f(v0[j]) + e1 * b2f(v1[j]);
    }
    if (i < end) {
        int s0 = csr_src[i];
        float e0 = ex_csr[(size_t)i * 4 + head];
        short8 v0 = *(const short8*)&hs[(size_t)s0 * HDIM + l32 * 8];
        den += e0;
#pragma unroll
        for (int j = 0; j < 8; ++j)
            acc[j] += e0 * b2f(v0[j]);
    }

    float inv = den > 0.f ? __builtin_amdgcn_rcpf(den) : 0.f;
    const float4* bp = (const float4*)(bias + l32 * 8);
    float4 bi0 = bp[0], bi1 = bp[1];
    float bb_[8] = {bi0.x, bi0.y, bi0.z, bi0.w, bi1.x, bi1.y, bi1.z, bi1.w};

    float x[8];
#pragma unroll
    for (int j = 0; j < 8; ++j) x[j] = acc[j] * inv + bb_[j];

    float s1 = ((x[0] + x[1]) + (x[2] + x[3])) + ((x[4] + x[5]) + (x[6] + x[7]));
    float s2 = 0.f;
#pragma unroll
    for (int j = 0; j < 8; ++j) s2 += x[j] * x[j];
#pragma unroll
    for (int off = 1; off < 32; off <<= 1) {
        s1 += __shfl_xor(s1, off);
        s2 += __shfl_xor(s2, off);
    }
    float mu = s1 * (1.f / 256.f);
    float var = s2 * (1.f / 256.f) - mu * mu;
    float rstd = rsqrtf(var + LN_EPS);

    const float4* gp = (const float4*)(g + l32 * 8);
    const float4* lbp = (const float4*)(b + l32 * 8);
    float4 g0 = gp[0], g1 = gp[1];
    float4 lb0 = lbp[0], lb1 = lbp[1];
    float gg_[8] = {g0.x, g0.y, g0.z, g0.w, g1.x, g1.y, g1.z, g1.w};
    float lb_[8] = {lb0.x, lb0.y, lb0.z, lb0.w, lb1.x, lb1.y, lb1.z, lb1.w};

    float y[8];
#pragma unroll
    for (int j = 0; j < 8; ++j)
        y[j] = (x[j] - mu) * rstd * gg_[j] + lb_[j];

    if (res && valid) {
        short8 r = *(const short8*)&res[(size_t)d * HDIM + l32 * 8];
#pragma unroll
        for (int j = 0; j < 8; ++j) y[j] += b2f(r[j]);
    }

    short8 o;
#pragma unroll
    for (int j = 0; j < 8; ++j) {
        float e = __expf(y[j]) - 1.f;        // fast ELU negative branch
        float v = y[j] > 0.f ? y[j] : e;
        o[j] = f2b(v);
    }
    if (valid)
        *(short8*)&h_out[(size_t)d * HDIM + l32 * 8] = o;
}

// ---------------------------------------------------------------------------
// Pool: mean over incoming at-edges of h_addr -> pooled (bf16). 2 nodes/wave.
// ---------------------------------------------------------------------------
__global__ __launch_bounds__(256) void k_pool(
    const int* __restrict__ rp, const int* __restrict__ csr_src,
    const bf16* __restrict__ h, bf16* __restrict__ out, int n_dst)
{
    const int wvg  = (blockIdx.x * 256 + threadIdx.x) >> 6;
    const int lane = threadIdx.x & 63;
    const int half = lane >> 5;
    const int l32  = lane & 31;
    const int d    = wvg * 2 + half;
    if (wvg * 2 >= n_dst) return;
    const bool valid = d < n_dst;

    int beg = 0, end = 0;
    if (valid) { beg = rp[d]; end = rp[d + 1]; }

    float acc[8] = {};
    int i = beg;
    for (; i + 2 <= end; i += 2) {
        int s0 = csr_src[i], s1 = csr_src[i + 1];
        short8 v0 = *(const short8*)&h[(size_t)s0 * HDIM + l32 * 8];
        short8 v1 = *(const short8*)&h[(size_t)s1 * HDIM + l32 * 8];
#pragma unroll
        for (int j = 0; j < 8; ++j)
            acc[j] += b2f(v0[j]) + b2f(v1[j]);
    }
    if (i < end) {
        short8 v0 = *(const short8*)&h[(size_t)csr_src[i] * HDIM + l32 * 8];
#pragma unroll
        for (int j = 0; j < 8; ++j) acc[j] += b2f(v0[j]);
    }
    int deg = end - beg;
    float c = deg > 0 ? __builtin_amdgcn_rcpf((float)deg) : 1.f;
    short8 o;
#pragma unroll
    for (int j = 0; j < 8; ++j) o[j] = f2b(acc[j] * c);
    if (valid)
        *(short8*)&out[(size_t)d * HDIM + l32 * 8] = o;
}

// ---------------------------------------------------------------------------
extern "C" void kernel_launch(void* const* d_in, const int* in_sizes, int n_in,
                              void* d_out, int out_size, void* d_ws, size_t ws_size,
                              hipStream_t stream)
{
    const float* x_tx      = (const float*)d_in[0];
    const float* x_addr    = (const float*)d_in[1];
    const int* addr_idx_at = (const int*)d_in[2];
    const int* tx_idx_at   = (const int*)d_in[3];
    const int* tx_idx_ta   = (const int*)d_in[4];
    const int* addr_idx_ta = (const int*)d_in[5];
    const float* w_in_tx   = (const float*)d_in[6];
    const float* b_in_tx   = (const float*)d_in[7];
    const float* w_in_addr = (const float*)d_in[8];
    const float* b_in_addr = (const float*)d_in[9];
    const float* w_at[2]  = {(const float*)d_in[10], (const float*)d_in[18]};
    const float* as_at[2] = {(const float*)d_in[11], (const float*)d_in[19]};
    const float* ad_at[2] = {(const float*)d_in[12], (const float*)d_in[20]};
    const float* b_at[2]  = {(const float*)d_in[13], (const float*)d_in[21]};
    const float* w_ta[2]  = {(const float*)d_in[14], (const float*)d_in[22]};
    const float* as_ta[2] = {(const float*)d_in[15], (const float*)d_in[23]};
    const float* ad_ta[2] = {(const float*)d_in[16], (const float*)d_in[24]};
    const float* b_ta[2]  = {(const float*)d_in[17], (const float*)d_in[25]};
    const float* ln_g_tx   = (const float*)d_in[26];
    const float* ln_b_tx   = (const float*)d_in[27];
    const float* ln_g_addr = (const float*)d_in[28];
    const float* ln_b_addr = (const float*)d_in[29];
    const float* w_out     = (const float*)d_in[30];
    const float* b_out     = (const float*)d_in[31];

    // ---- workspace carve-out (256B aligned) ----
    char* p = (char*)d_ws;
    auto alloc = [&](size_t bytes) -> void* {
        void* r = (void*)p; p += (bytes + 255) & ~(size_t)255; return r;
    };
    bf16* h0_tx   = (bf16*)alloc((size_t)NTX * 64 * 2);
    bf16* h0_addr = (bf16*)alloc((size_t)NADDR * 64 * 2);
    bf16* h_tx    = (bf16*)alloc((size_t)NTX * HDIM * 2);
    bf16* h_addr  = (bf16*)alloc((size_t)NADDR * HDIM * 2);
    bf16* hs_a    = (bf16*)alloc((size_t)NADDR * HDIM * 2);
    bf16* hs_t    = (bf16*)alloc((size_t)NTX * HDIM * 2);   // also pooled buffer
    float* al_src_at = (float*)alloc((size_t)NADDR * 4 * 4);
    float* al_dst_at = (float*)alloc((size_t)NTX * 4 * 4);
    float* al_src_ta = (float*)alloc((size_t)NTX * 4 * 4);
    float* al_dst_ta = (float*)alloc((size_t)NADDR * 4 * 4);
    float* Vd_at  = (float*)alloc(HDIM * 4 * 4);
    float* Vd_ta  = (float*)alloc(HDIM * 4 * 4);
    float* ex_csr = (float*)alloc((size_t)NEDGE * 4 * 4);
    int* rp_at    = (int*)alloc((size_t)(NTX + 1) * 4);
    int* rp_ta    = (int*)alloc((size_t)(NADDR + 1) * 4);
    int* csr_src_at = (int*)alloc((size_t)NEDGE * 4);
    int* csr_dst_at = (int*)alloc((size_t)NEDGE * 4);
    int* csr_src_ta = (int*)alloc((size_t)NEDGE * 4);
    int* csr_dst_ta = (int*)alloc((size_t)NEDGE * 4);
    int* deg_tx   = (int*)alloc((size_t)NTX * 4);
    int* deg_addr = (int*)alloc((size_t)NADDR * 4);
    int* cur_tx   = (int*)alloc((size_t)NTX * 4);
    int* cur_addr = (int*)alloc((size_t)NADDR * 4);
    int* bsum_tx  = (int*)alloc(1024 * 4);
    int* bsum_ad  = (int*)alloc(1024 * 4);
    // transposed bf16 weights: Wt[n][k]
    bf16* wt_at[2], *wt_ta[2], *wt_out;
    wt_at[0] = (bf16*)alloc((size_t)64 * HDIM * 2);
    wt_ta[0] = (bf16*)alloc((size_t)64 * HDIM * 2);
    wt_at[1] = (bf16*)alloc((size_t)HDIM * HDIM * 2);
    wt_ta[1] = (bf16*)alloc((size_t)HDIM * HDIM * 2);
    wt_out   = (bf16*)alloc((size_t)HDIM * HDIM * 2);

    dim3 blk(256);
    const int EG = (NEDGE + 255) / 256;
    auto gemm_fb = [&](const float* A, const float* B, const float* bias, bf16* C,
                       int M, int N, int K) {
        dim3 grid((M + 63) / 64, N / 64);
        hipLaunchKernelGGL((gemm_t<float, bf16>), grid, blk, 0, stream, A, B, bias, C, M, N, K);
    };
    auto mfma_grid = [&](int M) {
        int nrow = (M + 127) / 128;
        int nchunk = (nrow + GTPB - 1) / GTPB;
        return dim3(nchunk * (HDIM / 128));
    };
    auto mfma = [&](const bf16* A, const bf16* Wt, const float* bias, bf16* C,
                    int M, int K) {
        hipLaunchKernelGGL((gemm_mfma<bf16>), mfma_grid(M), blk, 0, stream,
                           A, Wt, bias, C, M, HDIM, K);
    };

    // ---- weight transpose+convert (tiny) ----
    hipLaunchKernelGGL(transpose_w, dim3((64 * HDIM + 255) / 256), blk, 0, stream,
                       w_at[0], wt_at[0], 64, HDIM);
    hipLaunchKernelGGL(transpose_w, dim3((64 * HDIM + 255) / 256), blk, 0, stream,
                       w_ta[0], wt_ta[0], 64, HDIM);
    hipLaunchKernelGGL(transpose_w, dim3((HDIM * HDIM + 255) / 256), blk, 0, stream,
                       w_at[1], wt_at[1], HDIM, HDIM);
    hipLaunchKernelGGL(transpose_w, dim3((HDIM * HDIM + 255) / 256), blk, 0, stream,
                       w_ta[1], wt_ta[1], HDIM, HDIM);
    hipLaunchKernelGGL(transpose_w, dim3((HDIM * HDIM + 255) / 256), blk, 0, stream,
                       w_out, wt_out, HDIM, HDIM);

    // ---- CSR build for both relations ----
    hipMemsetAsync(deg_tx, 0, (size_t)NTX * 4, stream);
    hipMemsetAsync(deg_addr, 0, (size_t)NADDR * 4, stream);
    hipMemsetAsync(cur_tx, 0, (size_t)NTX * 4, stream);
    hipMemsetAsync(cur_addr, 0, (size_t)NADDR * 4, stream);
    hipLaunchKernelGGL(k_hist, dim3(EG), blk, 0, stream, tx_idx_at, deg_tx, NEDGE);
    hipLaunchKernelGGL(k_hist, dim3(EG), blk, 0, stream, addr_idx_ta, deg_addr, NEDGE);
    const int NB_tx = (NTX + 1023) / 1024, NB_ad = (NADDR + 1023) / 1024;
    hipLaunchKernelGGL(scan_partial, dim3(NB_tx), blk, 0, stream, deg_tx, bsum_tx, NTX);
    hipLaunchKernelGGL(scan_partial, dim3(NB_ad), blk, 0, stream, deg_addr, bsum_ad, NADDR);
    hipLaunchKernelGGL(scan_bsum, dim3(1), blk, 0, stream, bsum_tx, NB_tx, rp_at, NTX, NEDGE);
    hipLaunchKernelGGL(scan_bsum, dim3(1), blk, 0, stream, bsum_ad, NB_ad, rp_ta, NADDR, NEDGE);
    hipLaunchKernelGGL(scan_write, dim3(NB_tx), blk, 0, stream, deg_tx, bsum_tx, rp_at, NTX);
    hipLaunchKernelGGL(scan_write, dim3(NB_ad), blk, 0, stream, deg_addr, bsum_ad, rp_ta, NADDR);
    hipLaunchKernelGGL(k_scatter, dim3(EG), blk, 0, stream,
                       addr_idx_at, tx_idx_at, rp_at, cur_tx, csr_src_at, csr_dst_at, NEDGE);
    hipLaunchKernelGGL(k_scatter, dim3(EG), blk, 0, stream,
                       tx_idx_ta, addr_idx_ta, rp_ta, cur_addr, csr_src_ta, csr_dst_ta, NEDGE);

    // ---- input projections (fp32 path) ----
    gemm_fb(x_tx, w_in_tx, b_in_tx, h0_tx, NTX, 64, FTX);
    gemm_fb(x_addr, w_in_addr, b_in_addr, h0_addr, NADDR, 64, 64);

    for (int layer = 0; layer < 2; ++layer) {
        const int in_dim = layer ? HDIM : 64;
        const bf16* ftx = layer ? h_tx : h0_tx;
        const bf16* fad = layer ? h_addr : h0_addr;

        // projections for both relations (MFMA)
        mfma(fad, wt_at[layer], nullptr, hs_a, NADDR, in_dim);
        mfma(ftx, wt_ta[layer], nullptr, hs_t, NTX, in_dim);

        // attention logit halves
        hipLaunchKernelGGL(build_vd, dim3((in_dim * 4 + 255) / 256), blk, 0, stream,
                           w_at[layer], ad_at[layer], Vd_at, in_dim);
        hipLaunchKernelGGL(build_vd, dim3((in_dim * 4 + 255) / 256), blk, 0, stream,
                           w_ta[layer], ad_ta[layer], Vd_ta, in_dim);
        hipLaunchKernelGGL(attn_src, dim3((NADDR + 3) / 4), blk, 0, stream,
                           hs_a, as_at[layer], al_src_at, NADDR);
        hipLaunchKernelGGL(attn_src, dim3((NTX + 3) / 4), blk, 0, stream,
                           hs_t, as_ta[layer], al_src_ta, NTX);
        hipLaunchKernelGGL(attn_dst, dim3((NTX + 3) / 4), blk, 0, stream,
                           ftx, Vd_at, al_dst_at, NTX, in_dim);
        hipLaunchKernelGGL(attn_dst, dim3((NADDR + 3) / 4), blk, 0, stream,
                           fad, Vd_ta, al_dst_ta, NADDR, in_dim);

        // ---- relation at: aggregate into tx ----
        const bf16* res_tx = layer ? h_tx : nullptr;
        const bf16* res_ad = layer ? h_addr : nullptr;
        hipLaunchKernelGGL(edge_ex, dim3(EG), blk, 0, stream,
                           csr_src_at, csr_dst_at, al_src_at, al_dst_at, ex_csr, NEDGE);
        hipLaunchKernelGGL(aggregate_ln_elu, dim3((NTX + 7) / 8), blk, 0, stream,
                           rp_at, csr_src_at, ex_csr, hs_a,
                           b_at[layer], ln_g_tx, ln_b_tx, res_tx, h_tx, NTX);
        // ---- relation ta: aggregate into addr ----
        hipLaunchKernelGGL(edge_ex, dim3(EG), blk, 0, stream,
                           csr_src_ta, csr_dst_ta, al_src_ta, al_dst_ta, ex_csr, NEDGE);
        hipLaunchKernelGGL(aggregate_ln_elu, dim3((NADDR + 7) / 8), blk, 0, stream,
                           rp_ta, csr_src_ta, ex_csr, hs_t,
                           b_ta[layer], ln_g_addr, ln_b_addr, res_ad, h_addr, NADDR);
    }

    // ---- scatter-mean pooling (reuse at-CSR) + output projection (MFMA) ----
    hipLaunchKernelGGL(k_pool, dim3((NTX + 7) / 8), blk, 0, stream,
                       rp_at, csr_src_at, h_addr, hs_t, NTX);
    hipLaunchKernelGGL((gemm_mfma<float>), mfma_grid(NTX), blk, 0, stream,
                       hs_t, wt_out, b_out, (float*)d_out, NTX, HDIM, HDIM);
}

// Round 4
// 1447.807 us; speedup vs baseline: 1.0078x; 1.0078x over previous
//
#include <hip/hip_runtime.h>
#include <hip/hip_bf16.h>

#define NTX    100000
#define NADDR  200000
#define NEDGE  400000
#define FTX    165
#define HDIM   256
#define NEG_SLOPE 0.2f
#define LN_EPS 1e-5f
#define GTPB   2      // row-tiles per block in gemm_mfma

typedef __hip_bfloat16 bf16;
typedef __attribute__((ext_vector_type(8))) short short8;   // 8 bf16 = 4 VGPRs
typedef __attribute__((ext_vector_type(4))) float floatx4;

__device__ __forceinline__ float to_f(float x) { return x; }
__device__ __forceinline__ float to_f(bf16 x) { return __bfloat162float(x); }
__device__ __forceinline__ void from_f(float x, float& o) { o = x; }
__device__ __forceinline__ void from_f(float x, bf16& o) { o = __float2bfloat16(x); }

__device__ __forceinline__ float b2f(short s) {
    unsigned u = ((unsigned)(unsigned short)s) << 16;
    return __uint_as_float(u);
}
__device__ __forceinline__ short f2b(float x) {
    bf16 t = __float2bfloat16(x);
    return *reinterpret_cast<short*>(&t);
}

__device__ __forceinline__ float4 load_bf16x4(const bf16* p) {
    const __hip_bfloat162* q = (const __hip_bfloat162*)p;
    __hip_bfloat162 v0 = q[0], v1 = q[1];
    return make_float4(__bfloat162float(v0.x), __bfloat162float(v0.y),
                       __bfloat162float(v1.x), __bfloat162float(v1.y));
}
__device__ __forceinline__ void store_bf16x4(bf16* p, float4 v) {
    __hip_bfloat162* q = (__hip_bfloat162*)p;
    __hip_bfloat162 t0, t1;
    t0.x = __float2bfloat16(v.x); t0.y = __float2bfloat16(v.y);
    t1.x = __float2bfloat16(v.z); t1.y = __float2bfloat16(v.w);
    q[0] = t0; q[1] = t1;
}

// async global->LDS, 16B per lane. LDS dest = wave-uniform base + lane*16.
__device__ __forceinline__ void gload_lds16(const bf16* g, bf16* l) {
    __builtin_amdgcn_global_load_lds(
        (const __attribute__((address_space(1))) void*)g,
        (__attribute__((address_space(3))) void*)l, 16, 0, 0);
}

// ---------------------------------------------------------------------------
// fp32 SIMD GEMM (in-projections only). 64x64 tile, BK=16, 4x4 microtile.
// ---------------------------------------------------------------------------
template<typename TA, typename TC>
__global__ __launch_bounds__(256) void gemm_t(
    const TA* __restrict__ A, const float* __restrict__ B,
    const float* __restrict__ bias, TC* __restrict__ C,
    int M, int N, int K)
{
    __shared__ float As[16][64];
    __shared__ float Bs[16][64];
    const int t = threadIdx.x;
    const int row0 = blockIdx.x * 64;
    const int col0 = blockIdx.y * 64;
    const int tm = t >> 4, tn = t & 15;
    float acc[4][4] = {};
    for (int k0 = 0; k0 < K; k0 += 16) {
#pragma unroll
        for (int i = 0; i < 4; ++i) {
            int idx = t + 256 * i;
            int m = idx >> 4, kk = idx & 15;
            int r = row0 + m, c = k0 + kk;
            As[kk][m] = (r < M && c < K) ? to_f(A[(size_t)r * K + c]) : 0.f;
        }
#pragma unroll
        for (int i = 0; i < 4; ++i) {
            int idx = t + 256 * i;
            int kk = idx >> 6, n = idx & 63;
            int r = k0 + kk;
            Bs[kk][n] = (r < K) ? B[(size_t)r * N + col0 + n] : 0.f;
        }
        __syncthreads();
#pragma unroll
        for (int kk = 0; kk < 16; ++kk) {
            const float4 a4 = *(const float4*)&As[kk][tm * 4];
            const float4 b4 = *(const float4*)&Bs[kk][tn * 4];
            float a_[4] = {a4.x, a4.y, a4.z, a4.w};
            float b_[4] = {b4.x, b4.y, b4.z, b4.w};
#pragma unroll
            for (int i = 0; i < 4; ++i)
#pragma unroll
                for (int j = 0; j < 4; ++j)
                    acc[i][j] += a_[i] * b_[j];
        }
        __syncthreads();
    }
    float4 bv = make_float4(0.f, 0.f, 0.f, 0.f);
    if (bias) bv = *(const float4*)&bias[col0 + tn * 4];
#pragma unroll
    for (int i = 0; i < 4; ++i) {
        int r = row0 + tm * 4 + i;
        if (r < M) {
            TC* cp = &C[(size_t)r * N + col0 + tn * 4];
            from_f(acc[i][0] + bv.x, cp[0]);
            from_f(acc[i][1] + bv.y, cp[1]);
            from_f(acc[i][2] + bv.z, cp[2]);
            from_f(acc[i][3] + bv.w, cp[3]);
        }
    }
}

// ---------------------------------------------------------------------------
// Wt[n,k] = bf16(W[k,n])  (one-time weight transpose+convert)
// ---------------------------------------------------------------------------
__global__ void transpose_w(const float* __restrict__ W, bf16* __restrict__ Wt,
                            int K, int N)
{
    int idx = blockIdx.x * blockDim.x + threadIdx.x;
    if (idx >= K * N) return;
    int k = idx / N, n = idx - k * N;
    Wt[(size_t)n * K + k] = __float2bfloat16(W[idx]);
}

// ---------------------------------------------------------------------------
// MFMA bf16 GEMM: C[M,N] = A[M,K] @ Wt[N,K]^T (+bias).
// 128x128 tile, BK=32, 4 waves. Double-buffered pipeline with COUNTED vmcnt
// (T4): every stage issues exactly 4 VMEM ops/thread (rows CLAMPED, not
// guarded, so the count is wave-uniform). Iteration:
//   stage(next buf) ; s_waitcnt vmcnt(4)  <- waits only for PREVIOUS stage,
//   raw s_barrier                            fresh 4 loads stay in flight
//   ds_read cur + MFMA (+epilogue)           across the whole compute phase
//   raw s_barrier                         <- WAR before next overwrite
// Raw s_barrier (not __syncthreads) avoids the compiler's vmcnt(0) drain.
// Swizzle: chunk-XOR on global SOURCE and ds_read address (involution).
// ---------------------------------------------------------------------------
template<typename TC>
__global__ __launch_bounds__(256) void gemm_mfma(
    const bf16* __restrict__ A, const bf16* __restrict__ Wt,
    const float* __restrict__ bias, TC* __restrict__ C,
    int M, int N, int K)
{
    __shared__ __align__(16) bf16 As[2][128 * 32];
    __shared__ __align__(16) bf16 Bs[2][128 * 32];
    const int t = threadIdx.x;
    const int wv = t >> 6, lane = t & 63;
    const int l15 = lane & 15, quad = lane >> 4;

    // bijective XCD-chunked block swizzle (m204)
    const int nbk = gridDim.x;
    const int orig = blockIdx.x;
    const int q = nbk >> 3, rrm = nbk & 7;
    const int xcd = orig & 7, jj = orig >> 3;
    const int wgid = (xcd < rrm ? xcd * (q + 1) : rrm * (q + 1) + (xcd - rrm) * q) + jj;
    const int ncol = N >> 7;
    const int chunk = wgid / ncol, bcol = wgid - chunk * ncol;
    const int col0 = bcol * 128;
    const int wrow = (wv >> 1) * 64, wcol = (wv & 1) * 64;

    const int nrow = (M + 127) >> 7;
    const int tile0 = chunk * GTPB;
    const int ntile = min(GTPB, nrow - tile0);
    const int KT = K >> 5;
    const int S = ntile * KT;

    // per-thread staging geometry: idx = t + 256*i covers 512 slots of 16B
    int rr_[2], ofs_[2], lds_[2];
#pragma unroll
    for (int i = 0; i < 2; ++i) {
        int idx = t + 256 * i;
        int r = idx >> 2, ch = idx & 3;
        int chs = ch ^ ((r >> 1) & 3);          // source-side swizzle
        rr_[i] = r;
        ofs_[i] = chs * 8;
        lds_[i] = (idx >> 6) * 512;             // wave-uniform base slot
    }

    // ds_read fragment offsets (loop-invariant), read-side swizzle
    int offA[4], offB[4];
#pragma unroll
    for (int rb = 0; rb < 4; ++rb) {
        int ra = wrow + rb * 16 + l15;
        offA[rb] = ra * 32 + ((quad ^ ((ra >> 1) & 3)) * 8);
        int rc = wcol + rb * 16 + l15;
        offB[rb] = rc * 32 + ((quad ^ ((rc >> 1) & 3)) * 8);
    }

    // always 4 VMEM ops per thread per stage: A rows clamped (not guarded) so
    // vmcnt counting is wave-uniform; garbage rows are masked at the C-write.
    auto stage = [&](int buf, int tt, int ks) {
        const int row0 = (tile0 + tt) << 7;
        const int k0 = ks << 5;
#pragma unroll
        for (int i = 0; i < 2; ++i) {
            int r = min(row0 + rr_[i], M - 1);
            gload_lds16(A + (size_t)r * K + k0 + ofs_[i], &As[buf][lds_[i]]);
            gload_lds16(Wt + (size_t)(col0 + rr_[i]) * K + k0 + ofs_[i],
                        &Bs[buf][lds_[i]]);
        }
    };

    floatx4 acc[4][4] = {};

    stage(0, 0, 0);

    int buf = 0, tt = 0, ks = 0;
    for (int s = 0; s < S; ++s) {
        int nks = ks + 1, ntt = tt;
        if (nks == KT) { nks = 0; ntt = tt + 1; }
        if (s + 1 < S) {
            stage(buf ^ 1, ntt, nks);            // prefetch next K-step
            asm volatile("s_waitcnt vmcnt(4)" ::: "memory");
        } else {
            asm volatile("s_waitcnt vmcnt(0)" ::: "memory");
        }
        __builtin_amdgcn_s_barrier();            // staged data visible

        short8 af[4], bfr[4];
#pragma unroll
        for (int rb = 0; rb < 4; ++rb) af[rb] = *(const short8*)&As[buf][offA[rb]];
#pragma unroll
        for (int nbb = 0; nbb < 4; ++nbb) bfr[nbb] = *(const short8*)&Bs[buf][offB[nbb]];
#pragma unroll
        for (int rb = 0; rb < 4; ++rb)
#pragma unroll
            for (int nbb = 0; nbb < 4; ++nbb)
                acc[rb][nbb] = __builtin_amdgcn_mfma_f32_16x16x32_bf16(
                    af[rb], bfr[nbb], acc[rb][nbb], 0, 0, 0);

        if (ks == KT - 1) {                      // tile finished: epilogue
            const int row0 = (tile0 + tt) << 7;
#pragma unroll
            for (int rb = 0; rb < 4; ++rb)
#pragma unroll
                for (int nbb = 0; nbb < 4; ++nbb) {
                    int col = col0 + wcol + nbb * 16 + l15;
                    float bv = bias ? bias[col] : 0.f;
#pragma unroll
                    for (int r = 0; r < 4; ++r) {
                        int row = row0 + wrow + rb * 16 + quad * 4 + r;
                        if (row < M)
                            from_f(acc[rb][nbb][r] + bv, C[(size_t)row * N + col]);
                    }
                    acc[rb][nbb] = floatx4{0.f, 0.f, 0.f, 0.f};
                }
        }

        __builtin_amdgcn_s_barrier();            // WAR: cur fully read
        buf ^= 1; tt = ntt; ks = nks;
    }
}

// ---------------------------------------------------------------------------
// Vd[k,h] = sum_j W[k, h*64+j] * a_d[h,j]
// ---------------------------------------------------------------------------
__global__ void build_vd(const float* __restrict__ W, const float* __restrict__ a_d,
                         float* __restrict__ Vd, int K)
{
    int idx = blockIdx.x * blockDim.x + threadIdx.x;  // k*4+h
    if (idx >= K * 4) return;
    int k = idx >> 2, h = idx & 3;
    float d = 0.f;
    for (int j = 0; j < 64; ++j)
        d += W[(size_t)k * HDIM + h * 64 + j] * a_d[h * 64 + j];
    Vd[idx] = d;
}

// ---------------------------------------------------------------------------
// al_dst[n,h] = sum_k X[n,k] * V[k,h].  Wave per row, bf16x4 loads.
// ---------------------------------------------------------------------------
__global__ __launch_bounds__(256) void attn_dst(
    const bf16* __restrict__ X, const float* __restrict__ V,
    float* __restrict__ out, int M, int K)
{
    int n = (blockIdx.x * 256 + threadIdx.x) >> 6;
    int lane = threadIdx.x & 63;
    if (n >= M) return;
    const bf16* xr = X + (size_t)n * K;
    float a0 = 0.f, a1 = 0.f, a2 = 0.f, a3 = 0.f;
    for (int k0 = lane * 4; k0 < K; k0 += 256) {
        float4 x = load_bf16x4(xr + k0);
        float xv[4] = {x.x, x.y, x.z, x.w};
#pragma unroll
        for (int j = 0; j < 4; ++j) {
            const float4 v = *(const float4*)&V[(k0 + j) * 4];
            a0 += xv[j] * v.x; a1 += xv[j] * v.y;
            a2 += xv[j] * v.z; a3 += xv[j] * v.w;
        }
    }
#pragma unroll
    for (int off = 32; off; off >>= 1) {
        a0 += __shfl_xor(a0, off); a1 += __shfl_xor(a1, off);
        a2 += __shfl_xor(a2, off); a3 += __shfl_xor(a3, off);
    }
    if (lane == 0) {
        out[(size_t)n * 4 + 0] = a0; out[(size_t)n * 4 + 1] = a1;
        out[(size_t)n * 4 + 2] = a2; out[(size_t)n * 4 + 3] = a3;
    }
}

// ---------------------------------------------------------------------------
// al_src[n,h] = sum_j hs[n, h*64+j] * a_s[h,j].  Wave per row (hs 256-wide).
// ---------------------------------------------------------------------------
__global__ __launch_bounds__(256) void attn_src(
    const bf16* __restrict__ hs, const float* __restrict__ a_s,
    float* __restrict__ out, int M)
{
    int n = (blockIdx.x * 256 + threadIdx.x) >> 6;
    int lane = threadIdx.x & 63;
    if (n >= M) return;
    float4 v = load_bf16x4(hs + (size_t)n * HDIM + lane * 4);
    float4 a = *(const float4*)&a_s[lane * 4];
    float s = v.x * a.x + v.y * a.y + v.z * a.z + v.w * a.w;
#pragma unroll
    for (int off = 1; off < 16; off <<= 1) s += __shfl_xor(s, off);
    if ((lane & 15) == 0) out[(size_t)n * 4 + (lane >> 4)] = s;
}

// ---------------------------------------------------------------------------
// CSR build: histogram, 3-phase exclusive scan, scatter (writes csr_src/dst).
// ---------------------------------------------------------------------------
__global__ void k_hist(const int* __restrict__ dst, int* __restrict__ deg, int E)
{
    int e = blockIdx.x * blockDim.x + threadIdx.x;
    if (e < E) atomicAdd(&deg[dst[e]], 1);
}

__global__ void scan_partial(const int* __restrict__ deg, int* __restrict__ bsum, int N)
{
    __shared__ int lds[256];
    int base = blockIdx.x * 1024, t = threadIdx.x;
    int s = 0;
#pragma unroll
    for (int i = 0; i < 4; ++i) {
        int idx = base + t * 4 + i;
        if (idx < N) s += deg[idx];
    }
    lds[t] = s; __syncthreads();
    for (int off = 128; off; off >>= 1) {
        if (t < off) lds[t] += lds[t + off];
        __syncthreads();
    }
    if (t == 0) bsum[blockIdx.x] = lds[0];
}

__global__ void scan_bsum(int* __restrict__ bsum, int NB, int* __restrict__ rp, int N, int E)
{
    if (threadIdx.x == 0 && blockIdx.x == 0) {
        int acc = 0;
        for (int b = 0; b < NB; ++b) { int v = bsum[b]; bsum[b] = acc; acc += v; }
        rp[N] = E;
    }
}

__global__ void scan_write(const int* __restrict__ deg, const int* __restrict__ bsum,
                           int* __restrict__ rp, int N)
{
    __shared__ int lds[256];
    int base = blockIdx.x * 1024, t = threadIdx.x;
    int v[4]; int s = 0;
#pragma unroll
    for (int i = 0; i < 4; ++i) {
        int idx = base + t * 4 + i;
        v[i] = (idx < N) ? deg[idx] : 0;
        s += v[i];
    }
    lds[t] = s; __syncthreads();
    for (int off = 1; off < 256; off <<= 1) {
        int x = (t >= off) ? lds[t - off] : 0;
        __syncthreads();
        lds[t] += x;
        __syncthreads();
    }
    int excl = lds[t] - s + bsum[blockIdx.x];
#pragma unroll
    for (int i = 0; i < 4; ++i) {
        int idx = base + t * 4 + i;
        if (idx < N) rp[idx] = excl;
        excl += v[i];
    }
}

__global__ void k_scatter(const int* __restrict__ src, const int* __restrict__ dst,
                          const int* __restrict__ rp, int* __restrict__ cur,
                          int* __restrict__ csr_src, int* __restrict__ csr_dst, int E)
{
    int e = blockIdx.x * blockDim.x + threadIdx.x;
    if (e >= E) return;
    int d = dst[e];
    int pos = atomicAdd(&cur[d], 1);
    int p = rp[d] + pos;
    csr_src[p] = src[e];
    csr_dst[p] = d;
}

// ---------------------------------------------------------------------------
// Edge-parallel: ex_csr[i][h] = exp(leaky(al_src[csr_src[i]][h] + al_dst[csr_dst[i]][h]))
// ---------------------------------------------------------------------------
__global__ void edge_ex(const int* __restrict__ csr_src, const int* __restrict__ csr_dst,
                        const float* __restrict__ al_src, const float* __restrict__ al_dst,
                        float* __restrict__ ex_csr, int E)
{
    int i = blockIdx.x * blockDim.x + threadIdx.x;
    if (i >= E) return;
    int s = csr_src[i], d = csr_dst[i];
    float4 as4 = *(const float4*)&al_src[(size_t)s * 4];
    float4 ad4 = *(const float4*)&al_dst[(size_t)d * 4];
    float l[4] = {as4.x + ad4.x, as4.y + ad4.y, as4.z + ad4.z, as4.w + ad4.w};
    float4 o;
    float* op = (float*)&o;
#pragma unroll
    for (int h = 0; h < 4; ++h) {
        float v = l[h] >= 0.f ? l[h] : NEG_SLOPE * l[h];
        op[h] = __expf(v);
    }
    *(float4*)&ex_csr[(size_t)i * 4] = o;
}

// ---------------------------------------------------------------------------
// Fused per-dst-node: softmax-weighted gather (CSR, precomputed ex) + bias
// + LayerNorm (+residual) + ELU -> h_out (bf16). 2 nodes/wave, 16B gathers.
// ---------------------------------------------------------------------------
__global__ __launch_bounds__(256) void aggregate_ln_elu(
    const int* __restrict__ rp, const int* __restrict__ csr_src,
    const float* __restrict__ ex_csr, const bf16* __restrict__ hs,
    const float* __restrict__ bias, const float* __restrict__ g,
    const float* __restrict__ b,
    const bf16* __restrict__ res, bf16* __restrict__ h_out, int n_dst)
{
    const int wvg  = (blockIdx.x * 256 + threadIdx.x) >> 6;  // global wave id
    const int lane = threadIdx.x & 63;
    const int half = lane >> 5;           // which node of the pair
    const int l32  = lane & 31;           // lane within node
    const int d    = wvg * 2 + half;
    if (wvg * 2 >= n_dst) return;
    const bool valid = d < n_dst;
    const int head = l32 >> 3;            // 8 lanes per head

    int beg = 0, end = 0;
    if (valid) { beg = rp[d]; end = rp[d + 1]; }

    float acc[8] = {};
    float den = 0.f;
    int i = beg;
    for (; i + 2 <= end; i += 2) {
        int s0 = csr_src[i], s1 = csr_src[i + 1];
        float e0 = ex_csr[(size_t)i * 4 + head];
        float e1 = ex_csr[(size_t)(i + 1) * 4 + head];
        short8 v0 = *(const short8*)&hs[(size_t)s0 * HDIM + l32 * 8];
        short8 v1 = *(const short8*)&hs[(size_t)s1 * HDIM + l32 * 8];
        den += e0 + e1;
#pragma unroll
        for (int j = 0; j < 8; ++j)
            acc[j] += e0 * b2f(v0[j]) + e1 * b2f(v1[j]);
    }
    if (i < end) {
        int s0 = csr_src[i];
        float e0 = ex_csr[(size_t)i * 4 + head];
        short8 v0 = *(const short8*)&hs[(size_t)s0 * HDIM + l32 * 8];
        den += e0;
#pragma unroll
        for (int j = 0; j < 8; ++j)
            acc[j] += e0 * b2f(v0[j]);
    }

    float inv = den > 0.f ? __builtin_amdgcn_rcpf(den) : 0.f;
    const float4* bp = (const float4*)(bias + l32 * 8);
    float4 bi0 = bp[0], bi1 = bp[1];
    float bb_[8] = {bi0.x, bi0.y, bi0.z, bi0.w, bi1.x, bi1.y, bi1.z, bi1.w};

    float x[8];
#pragma unroll
    for (int j = 0; j < 8; ++j) x[j] = acc[j] * inv + bb_[j];

    float s1 = ((x[0] + x[1]) + (x[2] + x[3])) + ((x[4] + x[5]) + (x[6] + x[7]));
    float s2 = 0.f;
#pragma unroll
    for (int j = 0; j < 8; ++j) s2 += x[j] * x[j];
#pragma unroll
    for (int off = 1; off < 32; off <<= 1) {
        s1 += __shfl_xor(s1, off);
        s2 += __shfl_xor(s2, off);
    }
    float mu = s1 * (1.f / 256.f);
    float var = s2 * (1.f / 256.f) - mu * mu;
    float rstd = rsqrtf(var + LN_EPS);

    const float4* gp = (const float4*)(g + l32 * 8);
    const float4* lbp = (const float4*)(b + l32 * 8);
    float4 g0 = gp[0], g1 = gp[1];
    float4 lb0 = lbp[0], lb1 = lbp[1];
    float gg_[8] = {g0.x, g0.y, g0.z, g0.w, g1.x, g1.y, g1.z, g1.w};
    float lb_[8] = {lb0.x, lb0.y, lb0.z, lb0.w, lb1.x, lb1.y, lb1.z, lb1.w};

    float y[8];
#pragma unroll
    for (int j = 0; j < 8; ++j)
        y[j] = (x[j] - mu) * rstd * gg_[j] + lb_[j];

    if (res && valid) {
        short8 r = *(const short8*)&res[(size_t)d * HDIM + l32 * 8];
#pragma unroll
        for (int j = 0; j < 8; ++j) y[j] += b2f(r[j]);
    }

    short8 o;
#pragma unroll
    for (int j = 0; j < 8; ++j) {
        float e = __expf(y[j]) - 1.f;        // fast ELU negative branch
        float v = y[j] > 0.f ? y[j] : e;
        o[j] = f2b(v);
    }
    if (valid)
        *(short8*)&h_out[(size_t)d * HDIM + l32 * 8] = o;
}

// ---------------------------------------------------------------------------
// Pool: mean over incoming at-edges of h_addr -> pooled (bf16). 2 nodes/wave.
// ---------------------------------------------------------------------------
__global__ __launch_bounds__(256) void k_pool(
    const int* __restrict__ rp, const int* __restrict__ csr_src,
    const bf16* __restrict__ h, bf16* __restrict__ out, int n_dst)
{
    const int wvg  = (blockIdx.x * 256 + threadIdx.x) >> 6;
    const int lane = threadIdx.x & 63;
    const int half = lane >> 5;
    const int l32  = lane & 31;
    const int d    = wvg * 2 + half;
    if (wvg * 2 >= n_dst) return;
    const bool valid = d < n_dst;

    int beg = 0, end = 0;
    if (valid) { beg = rp[d]; end = rp[d + 1]; }

    float acc[8] = {};
    int i = beg;
    for (; i + 2 <= end; i += 2) {
        int s0 = csr_src[i], s1 = csr_src[i + 1];
        short8 v0 = *(const short8*)&h[(size_t)s0 * HDIM + l32 * 8];
        short8 v1 = *(const short8*)&h[(size_t)s1 * HDIM + l32 * 8];
#pragma unroll
        for (int j = 0; j < 8; ++j)
            acc[j] += b2f(v0[j]) + b2f(v1[j]);
    }
    if (i < end) {
        short8 v0 = *(const short8*)&h[(size_t)csr_src[i] * HDIM + l32 * 8];
#pragma unroll
        for (int j = 0; j < 8; ++j) acc[j] += b2f(v0[j]);
    }
    int deg = end - beg;
    float c = deg > 0 ? __builtin_amdgcn_rcpf((float)deg) : 1.f;
    short8 o;
#pragma unroll
    for (int j = 0; j < 8; ++j) o[j] = f2b(acc[j] * c);
    if (valid)
        *(short8*)&out[(size_t)d * HDIM + l32 * 8] = o;
}

// ---------------------------------------------------------------------------
extern "C" void kernel_launch(void* const* d_in, const int* in_sizes, int n_in,
                              void* d_out, int out_size, void* d_ws, size_t ws_size,
                              hipStream_t stream)
{
    const float* x_tx      = (const float*)d_in[0];
    const float* x_addr    = (const float*)d_in[1];
    const int* addr_idx_at = (const int*)d_in[2];
    const int* tx_idx_at   = (const int*)d_in[3];
    const int* tx_idx_ta   = (const int*)d_in[4];
    const int* addr_idx_ta = (const int*)d_in[5];
    const float* w_in_tx   = (const float*)d_in[6];
    const float* b_in_tx   = (const float*)d_in[7];
    const float* w_in_addr = (const float*)d_in[8];
    const float* b_in_addr = (const float*)d_in[9];
    const float* w_at[2]  = {(const float*)d_in[10], (const float*)d_in[18]};
    const float* as_at[2] = {(const float*)d_in[11], (const float*)d_in[19]};
    const float* ad_at[2] = {(const float*)d_in[12], (const float*)d_in[20]};
    const float* b_at[2]  = {(const float*)d_in[13], (const float*)d_in[21]};
    const float* w_ta[2]  = {(const float*)d_in[14], (const float*)d_in[22]};
    const float* as_ta[2] = {(const float*)d_in[15], (const float*)d_in[23]};
    const float* ad_ta[2] = {(const float*)d_in[16], (const float*)d_in[24]};
    const float* b_ta[2]  = {(const float*)d_in[17], (const float*)d_in[25]};
    const float* ln_g_tx   = (const float*)d_in[26];
    const float* ln_b_tx   = (const float*)d_in[27];
    const float* ln_g_addr = (const float*)d_in[28];
    const float* ln_b_addr = (const float*)d_in[29];
    const float* w_out     = (const float*)d_in[30];
    const float* b_out     = (const float*)d_in[31];

    // ---- workspace carve-out (256B aligned) ----
    char* p = (char*)d_ws;
    auto alloc = [&](size_t bytes) -> void* {
        void* r = (void*)p; p += (bytes + 255) & ~(size_t)255; return r;
    };
    bf16* h0_tx   = (bf16*)alloc((size_t)NTX * 64 * 2);
    bf16* h0_addr = (bf16*)alloc((size_t)NADDR * 64 * 2);
    bf16* h_tx    = (bf16*)alloc((size_t)NTX * HDIM * 2);
    bf16* h_addr  = (bf16*)alloc((size_t)NADDR * HDIM * 2);
    bf16* hs_a    = (bf16*)alloc((size_t)NADDR * HDIM * 2);
    bf16* hs_t    = (bf16*)alloc((size_t)NTX * HDIM * 2);   // also pooled buffer
    float* al_src_at = (float*)alloc((size_t)NADDR * 4 * 4);
    float* al_dst_at = (float*)alloc((size_t)NTX * 4 * 4);
    float* al_src_ta = (float*)alloc((size_t)NTX * 4 * 4);
    float* al_dst_ta = (float*)alloc((size_t)NADDR * 4 * 4);
    float* Vd_at  = (float*)alloc(HDIM * 4 * 4);
    float* Vd_ta  = (float*)alloc(HDIM * 4 * 4);
    float* ex_csr = (float*)alloc((size_t)NEDGE * 4 * 4);
    int* rp_at    = (int*)alloc((size_t)(NTX + 1) * 4);
    int* rp_ta    = (int*)alloc((size_t)(NADDR + 1) * 4);
    int* csr_src_at = (int*)alloc((size_t)NEDGE * 4);
    int* csr_dst_at = (int*)alloc((size_t)NEDGE * 4);
    int* csr_src_ta = (int*)alloc((size_t)NEDGE * 4);
    int* csr_dst_ta = (int*)alloc((size_t)NEDGE * 4);
    int* deg_tx   = (int*)alloc((size_t)NTX * 4);
    int* deg_addr = (int*)alloc((size_t)NADDR * 4);
    int* cur_tx   = (int*)alloc((size_t)NTX * 4);
    int* cur_addr = (int*)alloc((size_t)NADDR * 4);
    int* bsum_tx  = (int*)alloc(1024 * 4);
    int* bsum_ad  = (int*)alloc(1024 * 4);
    // transposed bf16 weights: Wt[n][k]
    bf16* wt_at[2], *wt_ta[2], *wt_out;
    wt_at[0] = (bf16*)alloc((size_t)64 * HDIM * 2);
    wt_ta[0] = (bf16*)alloc((size_t)64 * HDIM * 2);
    wt_at[1] = (bf16*)alloc((size_t)HDIM * HDIM * 2);
    wt_ta[1] = (bf16*)alloc((size_t)HDIM * HDIM * 2);
    wt_out   = (bf16*)alloc((size_t)HDIM * HDIM * 2);

    dim3 blk(256);
    const int EG = (NEDGE + 255) / 256;
    auto gemm_fb = [&](const float* A, const float* B, const float* bias, bf16* C,
                       int M, int N, int K) {
        dim3 grid((M + 63) / 64, N / 64);
        hipLaunchKernelGGL((gemm_t<float, bf16>), grid, blk, 0, stream, A, B, bias, C, M, N, K);
    };
    auto mfma_grid = [&](int M) {
        int nrow = (M + 127) / 128;
        int nchunk = (nrow + GTPB - 1) / GTPB;
        return dim3(nchunk * (HDIM / 128));
    };
    auto mfma = [&](const bf16* A, const bf16* Wt, const float* bias, bf16* C,
                    int M, int K) {
        hipLaunchKernelGGL((gemm_mfma<bf16>), mfma_grid(M), blk, 0, stream,
                           A, Wt, bias, C, M, HDIM, K);
    };

    // ---- weight transpose+convert (tiny) ----
    hipLaunchKernelGGL(transpose_w, dim3((64 * HDIM + 255) / 256), blk, 0, stream,
                       w_at[0], wt_at[0], 64, HDIM);
    hipLaunchKernelGGL(transpose_w, dim3((64 * HDIM + 255) / 256), blk, 0, stream,
                       w_ta[0], wt_ta[0], 64, HDIM);
    hipLaunchKernelGGL(transpose_w, dim3((HDIM * HDIM + 255) / 256), blk, 0, stream,
                       w_at[1], wt_at[1], HDIM, HDIM);
    hipLaunchKernelGGL(transpose_w, dim3((HDIM * HDIM + 255) / 256), blk, 0, stream,
                       w_ta[1], wt_ta[1], HDIM, HDIM);
    hipLaunchKernelGGL(transpose_w, dim3((HDIM * HDIM + 255) / 256), blk, 0, stream,
                       w_out, wt_out, HDIM, HDIM);

    // ---- CSR build for both relations ----
    hipMemsetAsync(deg_tx, 0, (size_t)NTX * 4, stream);
    hipMemsetAsync(deg_addr, 0, (size_t)NADDR * 4, stream);
    hipMemsetAsync(cur_tx, 0, (size_t)NTX * 4, stream);
    hipMemsetAsync(cur_addr, 0, (size_t)NADDR * 4, stream);
    hipLaunchKernelGGL(k_hist, dim3(EG), blk, 0, stream, tx_idx_at, deg_tx, NEDGE);
    hipLaunchKernelGGL(k_hist, dim3(EG), blk, 0, stream, addr_idx_ta, deg_addr, NEDGE);
    const int NB_tx = (NTX + 1023) / 1024, NB_ad = (NADDR + 1023) / 1024;
    hipLaunchKernelGGL(scan_partial, dim3(NB_tx), blk, 0, stream, deg_tx, bsum_tx, NTX);
    hipLaunchKernelGGL(scan_partial, dim3(NB_ad), blk, 0, stream, deg_addr, bsum_ad, NADDR);
    hipLaunchKernelGGL(scan_bsum, dim3(1), blk, 0, stream, bsum_tx, NB_tx, rp_at, NTX, NEDGE);
    hipLaunchKernelGGL(scan_bsum, dim3(1), blk, 0, stream, bsum_ad, NB_ad, rp_ta, NADDR, NEDGE);
    hipLaunchKernelGGL(scan_write, dim3(NB_tx), blk, 0, stream, deg_tx, bsum_tx, rp_at, NTX);
    hipLaunchKernelGGL(scan_write, dim3(NB_ad), blk, 0, stream, deg_addr, bsum_ad, rp_ta, NADDR);
    hipLaunchKernelGGL(k_scatter, dim3(EG), blk, 0, stream,
                       addr_idx_at, tx_idx_at, rp_at, cur_tx, csr_src_at, csr_dst_at, NEDGE);
    hipLaunchKernelGGL(k_scatter, dim3(EG), blk, 0, stream,
                       tx_idx_ta, addr_idx_ta, rp_ta, cur_addr, csr_src_ta, csr_dst_ta, NEDGE);

    // ---- input projections (fp32 path) ----
    gemm_fb(x_tx, w_in_tx, b_in_tx, h0_tx, NTX, 64, FTX);
    gemm_fb(x_addr, w_in_addr, b_in_addr, h0_addr, NADDR, 64, 64);

    for (int layer = 0; layer < 2; ++layer) {
        const int in_dim = layer ? HDIM : 64;
        const bf16* ftx = layer ? h_tx : h0_tx;
        const bf16* fad = layer ? h_addr : h0_addr;

        // projections for both relations (MFMA)
        mfma(fad, wt_at[layer], nullptr, hs_a, NADDR, in_dim);
        mfma(ftx, wt_ta[layer], nullptr, hs_t, NTX, in_dim);

        // attention logit halves
        hipLaunchKernelGGL(build_vd, dim3((in_dim * 4 + 255) / 256), blk, 0, stream,
                           w_at[layer], ad_at[layer], Vd_at, in_dim);
        hipLaunchKernelGGL(build_vd, dim3((in_dim * 4 + 255) / 256), blk, 0, stream,
                           w_ta[layer], ad_ta[layer], Vd_ta, in_dim);
        hipLaunchKernelGGL(attn_src, dim3((NADDR + 3) / 4), blk, 0, stream,
                           hs_a, as_at[layer], al_src_at, NADDR);
        hipLaunchKernelGGL(attn_src, dim3((NTX + 3) / 4), blk, 0, stream,
                           hs_t, as_ta[layer], al_src_ta, NTX);
        hipLaunchKernelGGL(attn_dst, dim3((NTX + 3) / 4), blk, 0, stream,
                           ftx, Vd_at, al_dst_at, NTX, in_dim);
        hipLaunchKernelGGL(attn_dst, dim3((NADDR + 3) / 4), blk, 0, stream,
                           fad, Vd_ta, al_dst_ta, NADDR, in_dim);

        // ---- relation at: aggregate into tx ----
        const bf16* res_tx = layer ? h_tx : nullptr;
        const bf16* res_ad = layer ? h_addr : nullptr;
        hipLaunchKernelGGL(edge_ex, dim3(EG), blk, 0, stream,
                           csr_src_at, csr_dst_at, al_src_at, al_dst_at, ex_csr, NEDGE);
        hipLaunchKernelGGL(aggregate_ln_elu, dim3((NTX + 7) / 8), blk, 0, stream,
                           rp_at, csr_src_at, ex_csr, hs_a,
                           b_at[layer], ln_g_tx, ln_b_tx, res_tx, h_tx, NTX);
        // ---- relation ta: aggregate into addr ----
        hipLaunchKernelGGL(edge_ex, dim3(EG), blk, 0, stream,
                           csr_src_ta, csr_dst_ta, al_src_ta, al_dst_ta, ex_csr, NEDGE);
        hipLaunchKernelGGL(aggregate_ln_elu, dim3((NADDR + 7) / 8), blk, 0, stream,
                           rp_ta, csr_src_ta, ex_csr, hs_t,
                           b_ta[layer], ln_g_addr, ln_b_addr, res_ad, h_addr, NADDR);
    }

    // ---- scatter-mean pooling (reuse at-CSR) + output projection (MFMA) ----
    hipLaunchKernelGGL(k_pool, dim3((NTX + 7) / 8), blk, 0, stream,
                       rp_at, csr_src_at, h_addr, hs_t, NTX);
    hipLaunchKernelGGL((gemm_mfma<float>), mfma_grid(NTX), blk, 0, stream,
                       hs_t, wt_out, b_out, (float*)d_out, NTX, HDIM, HDIM);
}

// Round 5
// 1265.924 us; speedup vs baseline: 1.1526x; 1.1437x over previous
//
#include <hip/hip_runtime.h>
#include <hip/hip_bf16.h>

#define NTX    100000
#define NADDR  200000
#define NEDGE  400000
#define FTX    165
#define HDIM   256
#define NEG_SLOPE 0.2f
#define LN_EPS 1e-5f

typedef __hip_bfloat16 bf16;
typedef __attribute__((ext_vector_type(8))) short short8;   // 8 bf16 = 4 VGPRs
typedef __attribute__((ext_vector_type(4))) float floatx4;

__device__ __forceinline__ float to_f(float x) { return x; }
__device__ __forceinline__ float to_f(bf16 x) { return __bfloat162float(x); }
__device__ __forceinline__ void from_f(float x, float& o) { o = x; }
__device__ __forceinline__ void from_f(float x, bf16& o) { o = __float2bfloat16(x); }

__device__ __forceinline__ float b2f(short s) {
    unsigned u = ((unsigned)(unsigned short)s) << 16;
    return __uint_as_float(u);
}
__device__ __forceinline__ short f2b(float x) {
    bf16 t = __float2bfloat16(x);
    return *reinterpret_cast<short*>(&t);
}

__device__ __forceinline__ float4 load_bf16x4(const bf16* p) {
    const __hip_bfloat162* q = (const __hip_bfloat162*)p;
    __hip_bfloat162 v0 = q[0], v1 = q[1];
    return make_float4(__bfloat162float(v0.x), __bfloat162float(v0.y),
                       __bfloat162float(v1.x), __bfloat162float(v1.y));
}
__device__ __forceinline__ void store_bf16x4(bf16* p, float4 v) {
    __hip_bfloat162* q = (__hip_bfloat162*)p;
    __hip_bfloat162 t0, t1;
    t0.x = __float2bfloat16(v.x); t0.y = __float2bfloat16(v.y);
    t1.x = __float2bfloat16(v.z); t1.y = __float2bfloat16(v.w);
    q[0] = t0; q[1] = t1;
}

// async global->LDS, 16B per lane. LDS dest = wave-uniform base + lane*16.
__device__ __forceinline__ void gload_lds16(const bf16* g, bf16* l) {
    __builtin_amdgcn_global_load_lds(
        (const __attribute__((address_space(1))) void*)g,
        (__attribute__((address_space(3))) void*)l, 16, 0, 0);
}

// ---------------------------------------------------------------------------
// fp32 SIMD GEMM (in-projections only). 64x64 tile, BK=16, 4x4 microtile.
// ---------------------------------------------------------------------------
template<typename TA, typename TC>
__global__ __launch_bounds__(256) void gemm_t(
    const TA* __restrict__ A, const float* __restrict__ B,
    const float* __restrict__ bias, TC* __restrict__ C,
    int M, int N, int K)
{
    __shared__ float As[16][64];
    __shared__ float Bs[16][64];
    const int t = threadIdx.x;
    const int row0 = blockIdx.x * 64;
    const int col0 = blockIdx.y * 64;
    const int tm = t >> 4, tn = t & 15;
    float acc[4][4] = {};
    for (int k0 = 0; k0 < K; k0 += 16) {
#pragma unroll
        for (int i = 0; i < 4; ++i) {
            int idx = t + 256 * i;
            int m = idx >> 4, kk = idx & 15;
            int r = row0 + m, c = k0 + kk;
            As[kk][m] = (r < M && c < K) ? to_f(A[(size_t)r * K + c]) : 0.f;
        }
#pragma unroll
        for (int i = 0; i < 4; ++i) {
            int idx = t + 256 * i;
            int kk = idx >> 6, n = idx & 63;
            int r = k0 + kk;
            Bs[kk][n] = (r < K) ? B[(size_t)r * N + col0 + n] : 0.f;
        }
        __syncthreads();
#pragma unroll
        for (int kk = 0; kk < 16; ++kk) {
            const float4 a4 = *(const float4*)&As[kk][tm * 4];
            const float4 b4 = *(const float4*)&Bs[kk][tn * 4];
            float a_[4] = {a4.x, a4.y, a4.z, a4.w};
            float b_[4] = {b4.x, b4.y, b4.z, b4.w};
#pragma unroll
            for (int i = 0; i < 4; ++i)
#pragma unroll
                for (int j = 0; j < 4; ++j)
                    acc[i][j] += a_[i] * b_[j];
        }
        __syncthreads();
    }
    float4 bv = make_float4(0.f, 0.f, 0.f, 0.f);
    if (bias) bv = *(const float4*)&bias[col0 + tn * 4];
#pragma unroll
    for (int i = 0; i < 4; ++i) {
        int r = row0 + tm * 4 + i;
        if (r < M) {
            TC* cp = &C[(size_t)r * N + col0 + tn * 4];
            from_f(acc[i][0] + bv.x, cp[0]);
            from_f(acc[i][1] + bv.y, cp[1]);
            from_f(acc[i][2] + bv.z, cp[2]);
            from_f(acc[i][3] + bv.w, cp[3]);
        }
    }
}

// ---------------------------------------------------------------------------
// Wt[n,k] = bf16(W[k,n])  (one-time weight transpose+convert)
// ---------------------------------------------------------------------------
__global__ void transpose_w(const float* __restrict__ W, bf16* __restrict__ Wt,
                            int K, int N)
{
    int idx = blockIdx.x * blockDim.x + threadIdx.x;
    if (idx >= K * N) return;
    int k = idx / N, n = idx - k * N;
    Wt[(size_t)n * K + k] = __float2bfloat16(W[idx]);
}

// ---------------------------------------------------------------------------
// MFMA bf16 GEMM: C[M,256] = A[M,K] @ Wt[256,K]^T (+bias).  N == 256 fixed.
// BM=64 x BN=256 block tile, BK=64, 4 waves side-by-side (each 64x64).
//   - block covers ALL output cols -> A fetched exactly once from HBM
//   - BK=64 halves barrier-drain count; K=64 dispatches are SINGLE-step
//   - single LDS buffer (40KB: A 8KB + B 32KB), plain __syncthreads loop
//     (R1-proven control flow; inter-block TLP at 4 blocks/CU hides latency)
//   - chunk-XOR involution swizzle on global SOURCE + ds_read (conflict-free)
//   - per-thread staging = 1 base + scalar strides (no per-step VALU storm)
// ---------------------------------------------------------------------------
template<typename TC>
__global__ __launch_bounds__(256, 4) void gemm_mfma(
    const bf16* __restrict__ A, const bf16* __restrict__ Wt,
    const float* __restrict__ bias, TC* __restrict__ C,
    int M, int N, int K)
{
    __shared__ __align__(16) bf16 As[64 * 64];     //  8 KB
    __shared__ __align__(16) bf16 Bs[256 * 64];    // 32 KB
    const int t = threadIdx.x;
    const int wv = t >> 6, lane = t & 63;
    const int l15 = lane & 15, quad = lane >> 4;
    const int row0 = blockIdx.x * 64;
    const int wcol = wv * 64;

    // staging geometry: 16B slot idx -> (r = idx>>3, ch = idx&7),
    // source chunk chs = ch ^ (r&7).  For idx = t + 256*i both ch and
    // (r&7) are i-invariant -> per-thread constant swizzled chunk offset.
    const int r0   = t >> 3;                        // 0..31
    const int chs  = ((t & 7) ^ (r0 & 7)) * 8;      // element offset in row
    const int ldsb = (t >> 6) * 512;                //元素 base, instr stride 2048
    const int rowA0 = min(row0 + r0, M - 1);        // clamped (last block only)
    const int rowA1 = min(row0 + r0 + 32, M - 1);

    // ds_read swizzle pieces: chunk c = ks*4 + quad, read at c ^ (l15&7)
    const int p3 = l15 & 7;

    floatx4 acc[4][4] = {};

    const int S = K >> 6;
    for (int s = 0; s < S; ++s) {
        const int k0 = s << 6;
        gload_lds16(A + (size_t)rowA0 * K + k0 + chs, &As[ldsb]);
        gload_lds16(A + (size_t)rowA1 * K + k0 + chs, &As[ldsb + 2048]);
#pragma unroll
        for (int i = 0; i < 8; ++i)
            gload_lds16(Wt + (size_t)(r0 + 32 * i) * K + k0 + chs,
                        &Bs[ldsb + i * 2048]);
        __syncthreads();

#pragma unroll
        for (int ks = 0; ks < 2; ++ks) {
            const int cc = ((ks * 4 + quad) ^ p3) * 8;   // swizzled chunk elem-off
            short8 af[4], bfr[4];
#pragma unroll
            for (int rb = 0; rb < 4; ++rb)
                af[rb] = *(const short8*)&As[(rb * 16 + l15) * 64 + cc];
#pragma unroll
            for (int nbb = 0; nbb < 4; ++nbb)
                bfr[nbb] = *(const short8*)&Bs[(wcol + nbb * 16 + l15) * 64 + cc];
#pragma unroll
            for (int rb = 0; rb < 4; ++rb)
#pragma unroll
                for (int nbb = 0; nbb < 4; ++nbb)
                    acc[rb][nbb] = __builtin_amdgcn_mfma_f32_16x16x32_bf16(
                        af[rb], bfr[nbb], acc[rb][nbb], 0, 0, 0);
        }
        if (s + 1 < S) __syncthreads();              // WAR before re-stage
    }

#pragma unroll
    for (int rb = 0; rb < 4; ++rb)
#pragma unroll
        for (int nbb = 0; nbb < 4; ++nbb) {
            int col = wcol + nbb * 16 + l15;
            float bv = bias ? bias[col] : 0.f;
#pragma unroll
            for (int r = 0; r < 4; ++r) {
                int row = row0 + rb * 16 + quad * 4 + r;
                if (row < M)
                    from_f(acc[rb][nbb][r] + bv, C[(size_t)row * N + col]);
            }
        }
}

// ---------------------------------------------------------------------------
// Vd[k,h] = sum_j W[k, h*64+j] * a_d[h,j]
// ---------------------------------------------------------------------------
__global__ void build_vd(const float* __restrict__ W, const float* __restrict__ a_d,
                         float* __restrict__ Vd, int K)
{
    int idx = blockIdx.x * blockDim.x + threadIdx.x;  // k*4+h
    if (idx >= K * 4) return;
    int k = idx >> 2, h = idx & 3;
    float d = 0.f;
    for (int j = 0; j < 64; ++j)
        d += W[(size_t)k * HDIM + h * 64 + j] * a_d[h * 64 + j];
    Vd[idx] = d;
}

// ---------------------------------------------------------------------------
// al_dst[n,h] = sum_k X[n,k] * V[k,h].  Wave per row, bf16x4 loads.
// ---------------------------------------------------------------------------
__global__ __launch_bounds__(256) void attn_dst(
    const bf16* __restrict__ X, const float* __restrict__ V,
    float* __restrict__ out, int M, int K)
{
    int n = (blockIdx.x * 256 + threadIdx.x) >> 6;
    int lane = threadIdx.x & 63;
    if (n >= M) return;
    const bf16* xr = X + (size_t)n * K;
    float a0 = 0.f, a1 = 0.f, a2 = 0.f, a3 = 0.f;
    for (int k0 = lane * 4; k0 < K; k0 += 256) {
        float4 x = load_bf16x4(xr + k0);
        float xv[4] = {x.x, x.y, x.z, x.w};
#pragma unroll
        for (int j = 0; j < 4; ++j) {
            const float4 v = *(const float4*)&V[(k0 + j) * 4];
            a0 += xv[j] * v.x; a1 += xv[j] * v.y;
            a2 += xv[j] * v.z; a3 += xv[j] * v.w;
        }
    }
#pragma unroll
    for (int off = 32; off; off >>= 1) {
        a0 += __shfl_xor(a0, off); a1 += __shfl_xor(a1, off);
        a2 += __shfl_xor(a2, off); a3 += __shfl_xor(a3, off);
    }
    if (lane == 0) {
        out[(size_t)n * 4 + 0] = a0; out[(size_t)n * 4 + 1] = a1;
        out[(size_t)n * 4 + 2] = a2; out[(size_t)n * 4 + 3] = a3;
    }
}

// ---------------------------------------------------------------------------
// al_src[n,h] = sum_j hs[n, h*64+j] * a_s[h,j].  Wave per row (hs 256-wide).
// ---------------------------------------------------------------------------
__global__ __launch_bounds__(256) void attn_src(
    const bf16* __restrict__ hs, const float* __restrict__ a_s,
    float* __restrict__ out, int M)
{
    int n = (blockIdx.x * 256 + threadIdx.x) >> 6;
    int lane = threadIdx.x & 63;
    if (n >= M) return;
    float4 v = load_bf16x4(hs + (size_t)n * HDIM + lane * 4);
    float4 a = *(const float4*)&a_s[lane * 4];
    float s = v.x * a.x + v.y * a.y + v.z * a.z + v.w * a.w;
#pragma unroll
    for (int off = 1; off < 16; off <<= 1) s += __shfl_xor(s, off);
    if ((lane & 15) == 0) out[(size_t)n * 4 + (lane >> 4)] = s;
}

// ---------------------------------------------------------------------------
// CSR build: histogram, 3-phase exclusive scan, scatter (writes csr_src/dst).
// ---------------------------------------------------------------------------
__global__ void k_hist(const int* __restrict__ dst, int* __restrict__ deg, int E)
{
    int e = blockIdx.x * blockDim.x + threadIdx.x;
    if (e < E) atomicAdd(&deg[dst[e]], 1);
}

__global__ void scan_partial(const int* __restrict__ deg, int* __restrict__ bsum, int N)
{
    __shared__ int lds[256];
    int base = blockIdx.x * 1024, t = threadIdx.x;
    int s = 0;
#pragma unroll
    for (int i = 0; i < 4; ++i) {
        int idx = base + t * 4 + i;
        if (idx < N) s += deg[idx];
    }
    lds[t] = s; __syncthreads();
    for (int off = 128; off; off >>= 1) {
        if (t < off) lds[t] += lds[t + off];
        __syncthreads();
    }
    if (t == 0) bsum[blockIdx.x] = lds[0];
}

__global__ void scan_bsum(int* __restrict__ bsum, int NB, int* __restrict__ rp, int N, int E)
{
    if (threadIdx.x == 0 && blockIdx.x == 0) {
        int acc = 0;
        for (int b = 0; b < NB; ++b) { int v = bsum[b]; bsum[b] = acc; acc += v; }
        rp[N] = E;
    }
}

__global__ void scan_write(const int* __restrict__ deg, const int* __restrict__ bsum,
                           int* __restrict__ rp, int N)
{
    __shared__ int lds[256];
    int base = blockIdx.x * 1024, t = threadIdx.x;
    int v[4]; int s = 0;
#pragma unroll
    for (int i = 0; i < 4; ++i) {
        int idx = base + t * 4 + i;
        v[i] = (idx < N) ? deg[idx] : 0;
        s += v[i];
    }
    lds[t] = s; __syncthreads();
    for (int off = 1; off < 256; off <<= 1) {
        int x = (t >= off) ? lds[t - off] : 0;
        __syncthreads();
        lds[t] += x;
        __syncthreads();
    }
    int excl = lds[t] - s + bsum[blockIdx.x];
#pragma unroll
    for (int i = 0; i < 4; ++i) {
        int idx = base + t * 4 + i;
        if (idx < N) rp[idx] = excl;
        excl += v[i];
    }
}

__global__ void k_scatter(const int* __restrict__ src, const int* __restrict__ dst,
                          const int* __restrict__ rp, int* __restrict__ cur,
                          int* __restrict__ csr_src, int* __restrict__ csr_dst, int E)
{
    int e = blockIdx.x * blockDim.x + threadIdx.x;
    if (e >= E) return;
    int d = dst[e];
    int pos = atomicAdd(&cur[d], 1);
    int p = rp[d] + pos;
    csr_src[p] = src[e];
    csr_dst[p] = d;
}

// ---------------------------------------------------------------------------
// Edge-parallel: ex_csr[i][h] = exp(leaky(al_src[csr_src[i]][h] + al_dst[csr_dst[i]][h]))
// ---------------------------------------------------------------------------
__global__ void edge_ex(const int* __restrict__ csr_src, const int* __restrict__ csr_dst,
                        const float* __restrict__ al_src, const float* __restrict__ al_dst,
                        float* __restrict__ ex_csr, int E)
{
    int i = blockIdx.x * blockDim.x + threadIdx.x;
    if (i >= E) return;
    int s = csr_src[i], d = csr_dst[i];
    float4 as4 = *(const float4*)&al_src[(size_t)s * 4];
    float4 ad4 = *(const float4*)&al_dst[(size_t)d * 4];
    float l[4] = {as4.x + ad4.x, as4.y + ad4.y, as4.z + ad4.z, as4.w + ad4.w};
    float4 o;
    float* op = (float*)&o;
#pragma unroll
    for (int h = 0; h < 4; ++h) {
        float v = l[h] >= 0.f ? l[h] : NEG_SLOPE * l[h];
        op[h] = __expf(v);
    }
    *(float4*)&ex_csr[(size_t)i * 4] = o;
}

// ---------------------------------------------------------------------------
// Fused per-dst-node: softmax-weighted gather (CSR, precomputed ex) + bias
// + LayerNorm (+residual) + ELU -> h_out (bf16). 2 nodes/wave, 16B gathers.
// ---------------------------------------------------------------------------
__global__ __launch_bounds__(256) void aggregate_ln_elu(
    const int* __restrict__ rp, const int* __restrict__ csr_src,
    const float* __restrict__ ex_csr, const bf16* __restrict__ hs,
    const float* __restrict__ bias, const float* __restrict__ g,
    const float* __restrict__ b,
    const bf16* __restrict__ res, bf16* __restrict__ h_out, int n_dst)
{
    const int wvg  = (blockIdx.x * 256 + threadIdx.x) >> 6;  // global wave id
    const int lane = threadIdx.x & 63;
    const int half = lane >> 5;           // which node of the pair
    const int l32  = lane & 31;           // lane within node
    const int d    = wvg * 2 + half;
    if (wvg * 2 >= n_dst) return;
    const bool valid = d < n_dst;
    const int head = l32 >> 3;            // 8 lanes per head

    int beg = 0, end = 0;
    if (valid) { beg = rp[d]; end = rp[d + 1]; }

    float acc[8] = {};
    float den = 0.f;
    int i = beg;
    for (; i + 2 <= end; i += 2) {
        int s0 = csr_src[i], s1 = csr_src[i + 1];
        float e0 = ex_csr[(size_t)i * 4 + head];
        float e1 = ex_csr[(size_t)(i + 1) * 4 + head];
        short8 v0 = *(const short8*)&hs[(size_t)s0 * HDIM + l32 * 8];
        short8 v1 = *(const short8*)&hs[(size_t)s1 * HDIM + l32 * 8];
        den += e0 + e1;
#pragma unroll
        for (int j = 0; j < 8; ++j)
            acc[j] += e0 * b2f(v0[j]) + e1 * b2f(v1[j]);
    }
    if (i < end) {
        int s0 = csr_src[i];
        float e0 = ex_csr[(size_t)i * 4 + head];
        short8 v0 = *(const short8*)&hs[(size_t)s0 * HDIM + l32 * 8];
        den += e0;
#pragma unroll
        for (int j = 0; j < 8; ++j)
            acc[j] += e0 * b2f(v0[j]);
    }

    float inv = den > 0.f ? __builtin_amdgcn_rcpf(den) : 0.f;
    const float4* bp = (const float4*)(bias + l32 * 8);
    float4 bi0 = bp[0], bi1 = bp[1];
    float bb_[8] = {bi0.x, bi0.y, bi0.z, bi0.w, bi1.x, bi1.y, bi1.z, bi1.w};

    float x[8];
#pragma unroll
    for (int j = 0; j < 8; ++j) x[j] = acc[j] * inv + bb_[j];

    float s1 = ((x[0] + x[1]) + (x[2] + x[3])) + ((x[4] + x[5]) + (x[6] + x[7]));
    float s2 = 0.f;
#pragma unroll
    for (int j = 0; j < 8; ++j) s2 += x[j] * x[j];
#pragma unroll
    for (int off = 1; off < 32; off <<= 1) {
        s1 += __shfl_xor(s1, off);
        s2 += __shfl_xor(s2, off);
    }
    float mu = s1 * (1.f / 256.f);
    float var = s2 * (1.f / 256.f) - mu * mu;
    float rstd = rsqrtf(var + LN_EPS);

    const float4* gp = (const float4*)(g + l32 * 8);
    const float4* lbp = (const float4*)(b + l32 * 8);
    float4 g0 = gp[0], g1 = gp[1];
    float4 lb0 = lbp[0], lb1 = lbp[1];
    float gg_[8] = {g0.x, g0.y, g0.z, g0.w, g1.x, g1.y, g1.z, g1.w};
    float lb_[8] = {lb0.x, lb0.y, lb0.z, lb0.w, lb1.x, lb1.y, lb1.z, lb1.w};

    float y[8];
#pragma unroll
    for (int j = 0; j < 8; ++j)
        y[j] = (x[j] - mu) * rstd * gg_[j] + lb_[j];

    if (res && valid) {
        short8 r = *(const short8*)&res[(size_t)d * HDIM + l32 * 8];
#pragma unroll
        for (int j = 0; j < 8; ++j) y[j] += b2f(r[j]);
    }

    short8 o;
#pragma unroll
    for (int j = 0; j < 8; ++j) {
        float e = __expf(y[j]) - 1.f;        // fast ELU negative branch
        float v = y[j] > 0.f ? y[j] : e;
        o[j] = f2b(v);
    }
    if (valid)
        *(short8*)&h_out[(size_t)d * HDIM + l32 * 8] = o;
}

// ---------------------------------------------------------------------------
// Pool: mean over incoming at-edges of h_addr -> pooled (bf16). 2 nodes/wave.
// ---------------------------------------------------------------------------
__global__ __launch_bounds__(256) void k_pool(
    const int* __restrict__ rp, const int* __restrict__ csr_src,
    const bf16* __restrict__ h, bf16* __restrict__ out, int n_dst)
{
    const int wvg  = (blockIdx.x * 256 + threadIdx.x) >> 6;
    const int lane = threadIdx.x & 63;
    const int half = lane >> 5;
    const int l32  = lane & 31;
    const int d    = wvg * 2 + half;
    if (wvg * 2 >= n_dst) return;
    const bool valid = d < n_dst;

    int beg = 0, end = 0;
    if (valid) { beg = rp[d]; end = rp[d + 1]; }

    float acc[8] = {};
    int i = beg;
    for (; i + 2 <= end; i += 2) {
        int s0 = csr_src[i], s1 = csr_src[i + 1];
        short8 v0 = *(const short8*)&h[(size_t)s0 * HDIM + l32 * 8];
        short8 v1 = *(const short8*)&h[(size_t)s1 * HDIM + l32 * 8];
#pragma unroll
        for (int j = 0; j < 8; ++j)
            acc[j] += b2f(v0[j]) + b2f(v1[j]);
    }
    if (i < end) {
        short8 v0 = *(const short8*)&h[(size_t)csr_src[i] * HDIM + l32 * 8];
#pragma unroll
        for (int j = 0; j < 8; ++j) acc[j] += b2f(v0[j]);
    }
    int deg = end - beg;
    float c = deg > 0 ? __builtin_amdgcn_rcpf((float)deg) : 1.f;
    short8 o;
#pragma unroll
    for (int j = 0; j < 8; ++j) o[j] = f2b(acc[j] * c);
    if (valid)
        *(short8*)&out[(size_t)d * HDIM + l32 * 8] = o;
}

// ---------------------------------------------------------------------------
extern "C" void kernel_launch(void* const* d_in, const int* in_sizes, int n_in,
                              void* d_out, int out_size, void* d_ws, size_t ws_size,
                              hipStream_t stream)
{
    const float* x_tx      = (const float*)d_in[0];
    const float* x_addr    = (const float*)d_in[1];
    const int* addr_idx_at = (const int*)d_in[2];
    const int* tx_idx_at   = (const int*)d_in[3];
    const int* tx_idx_ta   = (const int*)d_in[4];
    const int* addr_idx_ta = (const int*)d_in[5];
    const float* w_in_tx   = (const float*)d_in[6];
    const float* b_in_tx   = (const float*)d_in[7];
    const float* w_in_addr = (const float*)d_in[8];
    const float* b_in_addr = (const float*)d_in[9];
    const float* w_at[2]  = {(const float*)d_in[10], (const float*)d_in[18]};
    const float* as_at[2] = {(const float*)d_in[11], (const float*)d_in[19]};
    const float* ad_at[2] = {(const float*)d_in[12], (const float*)d_in[20]};
    const float* b_at[2]  = {(const float*)d_in[13], (const float*)d_in[21]};
    const float* w_ta[2]  = {(const float*)d_in[14], (const float*)d_in[22]};
    const float* as_ta[2] = {(const float*)d_in[15], (const float*)d_in[23]};
    const float* ad_ta[2] = {(const float*)d_in[16], (const float*)d_in[24]};
    const float* b_ta[2]  = {(const float*)d_in[17], (const float*)d_in[25]};
    const float* ln_g_tx   = (const float*)d_in[26];
    const float* ln_b_tx   = (const float*)d_in[27];
    const float* ln_g_addr = (const float*)d_in[28];
    const float* ln_b_addr = (const float*)d_in[29];
    const float* w_out     = (const float*)d_in[30];
    const float* b_out     = (const float*)d_in[31];

    // ---- workspace carve-out (256B aligned) ----
    char* p = (char*)d_ws;
    auto alloc = [&](size_t bytes) -> void* {
        void* r = (void*)p; p += (bytes + 255) & ~(size_t)255; return r;
    };
    bf16* h0_tx   = (bf16*)alloc((size_t)NTX * 64 * 2);
    bf16* h0_addr = (bf16*)alloc((size_t)NADDR * 64 * 2);
    bf16* h_tx    = (bf16*)alloc((size_t)NTX * HDIM * 2);
    bf16* h_addr  = (bf16*)alloc((size_t)NADDR * HDIM * 2);
    bf16* hs_a    = (bf16*)alloc((size_t)NADDR * HDIM * 2);
    bf16* hs_t    = (bf16*)alloc((size_t)NTX * HDIM * 2);   // also pooled buffer
    float* al_src_at = (float*)alloc((size_t)NADDR * 4 * 4);
    float* al_dst_at = (float*)alloc((size_t)NTX * 4 * 4);
    float* al_src_ta = (float*)alloc((size_t)NTX * 4 * 4);
    float* al_dst_ta = (float*)alloc((size_t)NADDR * 4 * 4);
    float* Vd_at  = (float*)alloc(HDIM * 4 * 4);
    float* Vd_ta  = (float*)alloc(HDIM * 4 * 4);
    float* ex_csr = (float*)alloc((size_t)NEDGE * 4 * 4);
    int* rp_at    = (int*)alloc((size_t)(NTX + 1) * 4);
    int* rp_ta    = (int*)alloc((size_t)(NADDR + 1) * 4);
    int* csr_src_at = (int*)alloc((size_t)NEDGE * 4);
    int* csr_dst_at = (int*)alloc((size_t)NEDGE * 4);
    int* csr_src_ta = (int*)alloc((size_t)NEDGE * 4);
    int* csr_dst_ta = (int*)alloc((size_t)NEDGE * 4);
    int* deg_tx   = (int*)alloc((size_t)NTX * 4);
    int* deg_addr = (int*)alloc((size_t)NADDR * 4);
    int* cur_tx   = (int*)alloc((size_t)NTX * 4);
    int* cur_addr = (int*)alloc((size_t)NADDR * 4);
    int* bsum_tx  = (int*)alloc(1024 * 4);
    int* bsum_ad  = (int*)alloc(1024 * 4);
    // transposed bf16 weights: Wt[n][k]
    bf16* wt_at[2], *wt_ta[2], *wt_out;
    wt_at[0] = (bf16*)alloc((size_t)64 * HDIM * 2);
    wt_ta[0] = (bf16*)alloc((size_t)64 * HDIM * 2);
    wt_at[1] = (bf16*)alloc((size_t)HDIM * HDIM * 2);
    wt_ta[1] = (bf16*)alloc((size_t)HDIM * HDIM * 2);
    wt_out   = (bf16*)alloc((size_t)HDIM * HDIM * 2);

    dim3 blk(256);
    const int EG = (NEDGE + 255) / 256;
    auto gemm_fb = [&](const float* A, const float* B, const float* bias, bf16* C,
                       int M, int N, int K) {
        dim3 grid((M + 63) / 64, N / 64);
        hipLaunchKernelGGL((gemm_t<float, bf16>), grid, blk, 0, stream, A, B, bias, C, M, N, K);
    };
    auto mfma_grid = [&](int M) { return dim3((M + 63) / 64); };
    auto mfma = [&](const bf16* A, const bf16* Wt, const float* bias, bf16* C,
                    int M, int K) {
        hipLaunchKernelGGL((gemm_mfma<bf16>), mfma_grid(M), blk, 0, stream,
                           A, Wt, bias, C, M, HDIM, K);
    };

    // ---- weight transpose+convert (tiny) ----
    hipLaunchKernelGGL(transpose_w, dim3((64 * HDIM + 255) / 256), blk, 0, stream,
                       w_at[0], wt_at[0], 64, HDIM);
    hipLaunchKernelGGL(transpose_w, dim3((64 * HDIM + 255) / 256), blk, 0, stream,
                       w_ta[0], wt_ta[0], 64, HDIM);
    hipLaunchKernelGGL(transpose_w, dim3((HDIM * HDIM + 255) / 256), blk, 0, stream,
                       w_at[1], wt_at[1], HDIM, HDIM);
    hipLaunchKernelGGL(transpose_w, dim3((HDIM * HDIM + 255) / 256), blk, 0, stream,
                       w_ta[1], wt_ta[1], HDIM, HDIM);
    hipLaunchKernelGGL(transpose_w, dim3((HDIM * HDIM + 255) / 256), blk, 0, stream,
                       w_out, wt_out, HDIM, HDIM);

    // ---- CSR build for both relations ----
    hipMemsetAsync(deg_tx, 0, (size_t)NTX * 4, stream);
    hipMemsetAsync(deg_addr, 0, (size_t)NADDR * 4, stream);
    hipMemsetAsync(cur_tx, 0, (size_t)NTX * 4, stream);
    hipMemsetAsync(cur_addr, 0, (size_t)NADDR * 4, stream);
    hipLaunchKernelGGL(k_hist, dim3(EG), blk, 0, stream, tx_idx_at, deg_tx, NEDGE);
    hipLaunchKernelGGL(k_hist, dim3(EG), blk, 0, stream, addr_idx_ta, deg_addr, NEDGE);
    const int NB_tx = (NTX + 1023) / 1024, NB_ad = (NADDR + 1023) / 1024;
    hipLaunchKernelGGL(scan_partial, dim3(NB_tx), blk, 0, stream, deg_tx, bsum_tx, NTX);
    hipLaunchKernelGGL(scan_partial, dim3(NB_ad), blk, 0, stream, deg_addr, bsum_ad, NADDR);
    hipLaunchKernelGGL(scan_bsum, dim3(1), blk, 0, stream, bsum_tx, NB_tx, rp_at, NTX, NEDGE);
    hipLaunchKernelGGL(scan_bsum, dim3(1), blk, 0, stream, bsum_ad, NB_ad, rp_ta, NADDR, NEDGE);
    hipLaunchKernelGGL(scan_write, dim3(NB_tx), blk, 0, stream, deg_tx, bsum_tx, rp_at, NTX);
    hipLaunchKernelGGL(scan_write, dim3(NB_ad), blk, 0, stream, deg_addr, bsum_ad, rp_ta, NADDR);
    hipLaunchKernelGGL(k_scatter, dim3(EG), blk, 0, stream,
                       addr_idx_at, tx_idx_at, rp_at, cur_tx, csr_src_at, csr_dst_at, NEDGE);
    hipLaunchKernelGGL(k_scatter, dim3(EG), blk, 0, stream,
                       tx_idx_ta, addr_idx_ta, rp_ta, cur_addr, csr_src_ta, csr_dst_ta, NEDGE);

    // ---- input projections (fp32 path) ----
    gemm_fb(x_tx, w_in_tx, b_in_tx, h0_tx, NTX, 64, FTX);
    gemm_fb(x_addr, w_in_addr, b_in_addr, h0_addr, NADDR, 64, 64);

    for (int layer = 0; layer < 2; ++layer) {
        const int in_dim = layer ? HDIM : 64;
        const bf16* ftx = layer ? h_tx : h0_tx;
        const bf16* fad = layer ? h_addr : h0_addr;

        // projections for both relations (MFMA)
        mfma(fad, wt_at[layer], nullptr, hs_a, NADDR, in_dim);
        mfma(ftx, wt_ta[layer], nullptr, hs_t, NTX, in_dim);

        // attention logit halves
        hipLaunchKernelGGL(build_vd, dim3((in_dim * 4 + 255) / 256), blk, 0, stream,
                           w_at[layer], ad_at[layer], Vd_at, in_dim);
        hipLaunchKernelGGL(build_vd, dim3((in_dim * 4 + 255) / 256), blk, 0, stream,
                           w_ta[layer], ad_ta[layer], Vd_ta, in_dim);
        hipLaunchKernelGGL(attn_src, dim3((NADDR + 3) / 4), blk, 0, stream,
                           hs_a, as_at[layer], al_src_at, NADDR);
        hipLaunchKernelGGL(attn_src, dim3((NTX + 3) / 4), blk, 0, stream,
                           hs_t, as_ta[layer], al_src_ta, NTX);
        hipLaunchKernelGGL(attn_dst, dim3((NTX + 3) / 4), blk, 0, stream,
                           ftx, Vd_at, al_dst_at, NTX, in_dim);
        hipLaunchKernelGGL(attn_dst, dim3((NADDR + 3) / 4), blk, 0, stream,
                           fad, Vd_ta, al_dst_ta, NADDR, in_dim);

        // ---- relation at: aggregate into tx ----
        const bf16* res_tx = layer ? h_tx : nullptr;
        const bf16* res_ad = layer ? h_addr : nullptr;
        hipLaunchKernelGGL(edge_ex, dim3(EG), blk, 0, stream,
                           csr_src_at, csr_dst_at, al_src_at, al_dst_at, ex_csr, NEDGE);
        hipLaunchKernelGGL(aggregate_ln_elu, dim3((NTX + 7) / 8), blk, 0, stream,
                           rp_at, csr_src_at, ex_csr, hs_a,
                           b_at[layer], ln_g_tx, ln_b_tx, res_tx, h_tx, NTX);
        // ---- relation ta: aggregate into addr ----
        hipLaunchKernelGGL(edge_ex, dim3(EG), blk, 0, stream,
                           csr_src_ta, csr_dst_ta, al_src_ta, al_dst_ta, ex_csr, NEDGE);
        hipLaunchKernelGGL(aggregate_ln_elu, dim3((NADDR + 7) / 8), blk, 0, stream,
                           rp_ta, csr_src_ta, ex_csr, hs_t,
                           b_ta[layer], ln_g_addr, ln_b_addr, res_ad, h_addr, NADDR);
    }

    // ---- scatter-mean pooling (reuse at-CSR) + output projection (MFMA) ----
    hipLaunchKernelGGL(k_pool, dim3((NTX + 7) / 8), blk, 0, stream,
                       rp_at, csr_src_at, h_addr, hs_t, NTX);
    hipLaunchKernelGGL((gemm_mfma<float>), mfma_grid(NTX), blk, 0, stream,
                       hs_t, wt_out, b_out, (float*)d_out, NTX, HDIM, HDIM);
}

// Round 6
// 1255.420 us; speedup vs baseline: 1.1623x; 1.0084x over previous
//
#include <hip/hip_runtime.h>
#include <hip/hip_bf16.h>

#define NTX    100000
#define NADDR  200000
#define NEDGE  400000
#define FTX    165
#define FTXP   192    // FTX zero-padded to a multiple of 64
#define HDIM   256
#define NEG_SLOPE 0.2f
#define LN_EPS 1e-5f

typedef __hip_bfloat16 bf16;
typedef __attribute__((ext_vector_type(8))) short short8;   // 8 bf16 = 4 VGPRs
typedef __attribute__((ext_vector_type(4))) float floatx4;

__device__ __forceinline__ float to_f(float x) { return x; }
__device__ __forceinline__ float to_f(bf16 x) { return __bfloat162float(x); }
__device__ __forceinline__ void from_f(float x, float& o) { o = x; }
__device__ __forceinline__ void from_f(float x, bf16& o) { o = __float2bfloat16(x); }

__device__ __forceinline__ float b2f(short s) {
    unsigned u = ((unsigned)(unsigned short)s) << 16;
    return __uint_as_float(u);
}
__device__ __forceinline__ short f2b(float x) {
    bf16 t = __float2bfloat16(x);
    return *reinterpret_cast<short*>(&t);
}

__device__ __forceinline__ float4 load_bf16x4(const bf16* p) {
    const __hip_bfloat162* q = (const __hip_bfloat162*)p;
    __hip_bfloat162 v0 = q[0], v1 = q[1];
    return make_float4(__bfloat162float(v0.x), __bfloat162float(v0.y),
                       __bfloat162float(v1.x), __bfloat162float(v1.y));
}
__device__ __forceinline__ void store_bf16x4(bf16* p, float4 v) {
    __hip_bfloat162* q = (__hip_bfloat162*)p;
    __hip_bfloat162 t0, t1;
    t0.x = __float2bfloat16(v.x); t0.y = __float2bfloat16(v.y);
    t1.x = __float2bfloat16(v.z); t1.y = __float2bfloat16(v.w);
    q[0] = t0; q[1] = t1;
}

// async global->LDS, 16B per lane. LDS dest = wave-uniform base + lane*16.
__device__ __forceinline__ void gload_lds16(const bf16* g, bf16* l) {
    __builtin_amdgcn_global_load_lds(
        (const __attribute__((address_space(1))) void*)g,
        (__attribute__((address_space(3))) void*)l, 16, 0, 0);
}

// ---------------------------------------------------------------------------
// fp32 -> bf16 convert with optional K zero-padding. 8 elems/thread.
// ---------------------------------------------------------------------------
__global__ void cvt_pad_bf16(const float* __restrict__ X, bf16* __restrict__ Y,
                             int M, int Kin, int Kout)
{
    int idx = blockIdx.x * blockDim.x + threadIdx.x;
    int c8pr = Kout >> 3;                 // 8-elem chunks per row
    if (idx >= M * c8pr) return;
    int row = idx / c8pr;
    int c0 = (idx - row * c8pr) << 3;
    const float* xr = X + (size_t)row * Kin + c0;
    short8 o;
#pragma unroll
    for (int j = 0; j < 8; ++j)
        o[j] = (c0 + j < Kin) ? f2b(xr[j]) : (short)0;
    *(short8*)&Y[(size_t)row * Kout + c0] = o;
}

// ---------------------------------------------------------------------------
// Wt[n,k] = bf16(W[k,n]) with K zero-padding (one-time weight transpose).
// ---------------------------------------------------------------------------
__global__ void transpose_w_pad(const float* __restrict__ W, bf16* __restrict__ Wt,
                                int Kin, int Kout, int N)
{
    int idx = blockIdx.x * blockDim.x + threadIdx.x;
    if (idx >= N * Kout) return;
    int n = idx / Kout, k = idx - n * Kout;
    Wt[idx] = (k < Kin) ? __float2bfloat16(W[(size_t)k * N + n])
                        : __float2bfloat16(0.f);
}

// ---------------------------------------------------------------------------
// MFMA bf16 GEMM: C[M,256] = A[M,K] @ Wt[256,K]^T (+bias).  N == 256 fixed.
// BM=64 x BN=256 tile, BK=64, 4 waves side-by-side (R4-proven structure).
// ---------------------------------------------------------------------------
template<typename TC>
__global__ __launch_bounds__(256, 4) void gemm_mfma(
    const bf16* __restrict__ A, const bf16* __restrict__ Wt,
    const float* __restrict__ bias, TC* __restrict__ C,
    int M, int N, int K)
{
    __shared__ __align__(16) bf16 As[64 * 64];     //  8 KB
    __shared__ __align__(16) bf16 Bs[256 * 64];    // 32 KB
    const int t = threadIdx.x;
    const int wv = t >> 6, lane = t & 63;
    const int l15 = lane & 15, quad = lane >> 4;
    const int row0 = blockIdx.x * 64;
    const int wcol = wv * 64;

    const int r0   = t >> 3;                        // 0..31
    const int chs  = ((t & 7) ^ (r0 & 7)) * 8;      // src-side swizzled chunk
    const int ldsb = (t >> 6) * 512;
    const int rowA0 = min(row0 + r0, M - 1);
    const int rowA1 = min(row0 + r0 + 32, M - 1);
    const int p3 = l15 & 7;

    floatx4 acc[4][4] = {};

    const int S = K >> 6;
    for (int s = 0; s < S; ++s) {
        const int k0 = s << 6;
        gload_lds16(A + (size_t)rowA0 * K + k0 + chs, &As[ldsb]);
        gload_lds16(A + (size_t)rowA1 * K + k0 + chs, &As[ldsb + 2048]);
#pragma unroll
        for (int i = 0; i < 8; ++i)
            gload_lds16(Wt + (size_t)(r0 + 32 * i) * K + k0 + chs,
                        &Bs[ldsb + i * 2048]);
        __syncthreads();

#pragma unroll
        for (int ks = 0; ks < 2; ++ks) {
            const int cc = ((ks * 4 + quad) ^ p3) * 8;   // read-side swizzle
            short8 af[4], bfr[4];
#pragma unroll
            for (int rb = 0; rb < 4; ++rb)
                af[rb] = *(const short8*)&As[(rb * 16 + l15) * 64 + cc];
#pragma unroll
            for (int nbb = 0; nbb < 4; ++nbb)
                bfr[nbb] = *(const short8*)&Bs[(wcol + nbb * 16 + l15) * 64 + cc];
#pragma unroll
            for (int rb = 0; rb < 4; ++rb)
#pragma unroll
                for (int nbb = 0; nbb < 4; ++nbb)
                    acc[rb][nbb] = __builtin_amdgcn_mfma_f32_16x16x32_bf16(
                        af[rb], bfr[nbb], acc[rb][nbb], 0, 0, 0);
        }
        if (s + 1 < S) __syncthreads();              // WAR before re-stage
    }

#pragma unroll
    for (int rb = 0; rb < 4; ++rb)
#pragma unroll
        for (int nbb = 0; nbb < 4; ++nbb) {
            int col = wcol + nbb * 16 + l15;
            float bv = bias ? bias[col] : 0.f;
#pragma unroll
            for (int r = 0; r < 4; ++r) {
                int row = row0 + rb * 16 + quad * 4 + r;
                if (row < M)
                    from_f(acc[rb][nbb][r] + bv, C[(size_t)row * N + col]);
            }
        }
}

// ---------------------------------------------------------------------------
// MFMA bf16 GEMM, N == 64 (input projections): C[M,64] = A[M,K]@Wt[64,K]^T.
// BM=64 x BN=64, BK=64, 4 waves; wave w owns cols w*16..w*16+15 (acc[4]).
// Same staging/swizzle scheme as gemm_mfma. 16 KB LDS, memory-bound target.
// ---------------------------------------------------------------------------
__global__ __launch_bounds__(256, 4) void gemm_mfma64(
    const bf16* __restrict__ A, const bf16* __restrict__ Wt,
    const float* __restrict__ bias, bf16* __restrict__ C,
    int M, int K)
{
    __shared__ __align__(16) bf16 As[64 * 64];     // 8 KB
    __shared__ __align__(16) bf16 Bs[64 * 64];     // 8 KB
    const int t = threadIdx.x;
    const int wv = t >> 6, lane = t & 63;
    const int l15 = lane & 15, quad = lane >> 4;
    const int row0 = blockIdx.x * 64;
    const int wcol = wv * 16;

    const int r0   = t >> 3;
    const int chs  = ((t & 7) ^ (r0 & 7)) * 8;
    const int ldsb = (t >> 6) * 512;
    const int rowA0 = min(row0 + r0, M - 1);
    const int rowA1 = min(row0 + r0 + 32, M - 1);
    const int p3 = l15 & 7;

    floatx4 acc[4] = {};

    const int S = K >> 6;
    for (int s = 0; s < S; ++s) {
        const int k0 = s << 6;
        gload_lds16(A + (size_t)rowA0 * K + k0 + chs, &As[ldsb]);
        gload_lds16(A + (size_t)rowA1 * K + k0 + chs, &As[ldsb + 2048]);
        gload_lds16(Wt + (size_t)r0 * K + k0 + chs, &Bs[ldsb]);
        gload_lds16(Wt + (size_t)(r0 + 32) * K + k0 + chs, &Bs[ldsb + 2048]);
        __syncthreads();

#pragma unroll
        for (int ks = 0; ks < 2; ++ks) {
            const int cc = ((ks * 4 + quad) ^ p3) * 8;
            short8 af[4];
#pragma unroll
            for (int rb = 0; rb < 4; ++rb)
                af[rb] = *(const short8*)&As[(rb * 16 + l15) * 64 + cc];
            short8 bfr = *(const short8*)&Bs[(wcol + l15) * 64 + cc];
#pragma unroll
            for (int rb = 0; rb < 4; ++rb)
                acc[rb] = __builtin_amdgcn_mfma_f32_16x16x32_bf16(
                    af[rb], bfr, acc[rb], 0, 0, 0);
        }
        if (s + 1 < S) __syncthreads();
    }

    const int col = wcol + l15;
    const float bv = bias ? bias[col] : 0.f;
#pragma unroll
    for (int rb = 0; rb < 4; ++rb)
#pragma unroll
        for (int r = 0; r < 4; ++r) {
            int row = row0 + rb * 16 + quad * 4 + r;
            if (row < M)
                from_f(acc[rb][r] + bv, C[(size_t)row * 64 + col]);
        }
}

// ---------------------------------------------------------------------------
// Vd[k,h] = sum_j W[k, h*64+j] * a_d[h,j]
// ---------------------------------------------------------------------------
__global__ void build_vd(const float* __restrict__ W, const float* __restrict__ a_d,
                         float* __restrict__ Vd, int K)
{
    int idx = blockIdx.x * blockDim.x + threadIdx.x;  // k*4+h
    if (idx >= K * 4) return;
    int k = idx >> 2, h = idx & 3;
    float d = 0.f;
    for (int j = 0; j < 64; ++j)
        d += W[(size_t)k * HDIM + h * 64 + j] * a_d[h * 64 + j];
    Vd[idx] = d;
}

// ---------------------------------------------------------------------------
// al_dst[n,h] = sum_k X[n,k] * V[k,h].  Wave per row, bf16x4 loads.
// ---------------------------------------------------------------------------
__global__ __launch_bounds__(256) void attn_dst(
    const bf16* __restrict__ X, const float* __restrict__ V,
    float* __restrict__ out, int M, int K)
{
    int n = (blockIdx.x * 256 + threadIdx.x) >> 6;
    int lane = threadIdx.x & 63;
    if (n >= M) return;
    const bf16* xr = X + (size_t)n * K;
    float a0 = 0.f, a1 = 0.f, a2 = 0.f, a3 = 0.f;
    for (int k0 = lane * 4; k0 < K; k0 += 256) {
        float4 x = load_bf16x4(xr + k0);
        float xv[4] = {x.x, x.y, x.z, x.w};
#pragma unroll
        for (int j = 0; j < 4; ++j) {
            const float4 v = *(const float4*)&V[(k0 + j) * 4];
            a0 += xv[j] * v.x; a1 += xv[j] * v.y;
            a2 += xv[j] * v.z; a3 += xv[j] * v.w;
        }
    }
#pragma unroll
    for (int off = 32; off; off >>= 1) {
        a0 += __shfl_xor(a0, off); a1 += __shfl_xor(a1, off);
        a2 += __shfl_xor(a2, off); a3 += __shfl_xor(a3, off);
    }
    if (lane == 0) {
        out[(size_t)n * 4 + 0] = a0; out[(size_t)n * 4 + 1] = a1;
        out[(size_t)n * 4 + 2] = a2; out[(size_t)n * 4 + 3] = a3;
    }
}

// ---------------------------------------------------------------------------
// al_src[n,h] = sum_j hs[n, h*64+j] * a_s[h,j].  Wave per row (hs 256-wide).
// ---------------------------------------------------------------------------
__global__ __launch_bounds__(256) void attn_src(
    const bf16* __restrict__ hs, const float* __restrict__ a_s,
    float* __restrict__ out, int M)
{
    int n = (blockIdx.x * 256 + threadIdx.x) >> 6;
    int lane = threadIdx.x & 63;
    if (n >= M) return;
    float4 v = load_bf16x4(hs + (size_t)n * HDIM + lane * 4);
    float4 a = *(const float4*)&a_s[lane * 4];
    float s = v.x * a.x + v.y * a.y + v.z * a.z + v.w * a.w;
#pragma unroll
    for (int off = 1; off < 16; off <<= 1) s += __shfl_xor(s, off);
    if ((lane & 15) == 0) out[(size_t)n * 4 + (lane >> 4)] = s;
}

// ---------------------------------------------------------------------------
// CSR build: histogram, 3-phase exclusive scan, scatter (writes csr_src/dst).
// ---------------------------------------------------------------------------
__global__ void k_hist(const int* __restrict__ dst, int* __restrict__ deg, int E)
{
    int e = blockIdx.x * blockDim.x + threadIdx.x;
    if (e < E) atomicAdd(&deg[dst[e]], 1);
}

__global__ void scan_partial(const int* __restrict__ deg, int* __restrict__ bsum, int N)
{
    __shared__ int lds[256];
    int base = blockIdx.x * 1024, t = threadIdx.x;
    int s = 0;
#pragma unroll
    for (int i = 0; i < 4; ++i) {
        int idx = base + t * 4 + i;
        if (idx < N) s += deg[idx];
    }
    lds[t] = s; __syncthreads();
    for (int off = 128; off; off >>= 1) {
        if (t < off) lds[t] += lds[t + off];
        __syncthreads();
    }
    if (t == 0) bsum[blockIdx.x] = lds[0];
}

__global__ void scan_bsum(int* __restrict__ bsum, int NB, int* __restrict__ rp, int N, int E)
{
    if (threadIdx.x == 0 && blockIdx.x == 0) {
        int acc = 0;
        for (int b = 0; b < NB; ++b) { int v = bsum[b]; bsum[b] = acc; acc += v; }
        rp[N] = E;
    }
}

__global__ void scan_write(const int* __restrict__ deg, const int* __restrict__ bsum,
                           int* __restrict__ rp, int N)
{
    __shared__ int lds[256];
    int base = blockIdx.x * 1024, t = threadIdx.x;
    int v[4]; int s = 0;
#pragma unroll
    for (int i = 0; i < 4; ++i) {
        int idx = base + t * 4 + i;
        v[i] = (idx < N) ? deg[idx] : 0;
        s += v[i];
    }
    lds[t] = s; __syncthreads();
    for (int off = 1; off < 256; off <<= 1) {
        int x = (t >= off) ? lds[t - off] : 0;
        __syncthreads();
        lds[t] += x;
        __syncthreads();
    }
    int excl = lds[t] - s + bsum[blockIdx.x];
#pragma unroll
    for (int i = 0; i < 4; ++i) {
        int idx = base + t * 4 + i;
        if (idx < N) rp[idx] = excl;
        excl += v[i];
    }
}

__global__ void k_scatter(const int* __restrict__ src, const int* __restrict__ dst,
                          const int* __restrict__ rp, int* __restrict__ cur,
                          int* __restrict__ csr_src, int* __restrict__ csr_dst, int E)
{
    int e = blockIdx.x * blockDim.x + threadIdx.x;
    if (e >= E) return;
    int d = dst[e];
    int pos = atomicAdd(&cur[d], 1);
    int p = rp[d] + pos;
    csr_src[p] = src[e];
    csr_dst[p] = d;
}

// ---------------------------------------------------------------------------
// Edge-parallel: ex_csr[i][h] = exp(leaky(al_src[csr_src[i]][h] + al_dst[csr_dst[i]][h]))
// ---------------------------------------------------------------------------
__global__ void edge_ex(const int* __restrict__ csr_src, const int* __restrict__ csr_dst,
                        const float* __restrict__ al_src, const float* __restrict__ al_dst,
                        float* __restrict__ ex_csr, int E)
{
    int i = blockIdx.x * blockDim.x + threadIdx.x;
    if (i >= E) return;
    int s = csr_src[i], d = csr_dst[i];
    float4 as4 = *(const float4*)&al_src[(size_t)s * 4];
    float4 ad4 = *(const float4*)&al_dst[(size_t)d * 4];
    float l[4] = {as4.x + ad4.x, as4.y + ad4.y, as4.z + ad4.z, as4.w + ad4.w};
    float4 o;
    float* op = (float*)&o;
#pragma unroll
    for (int h = 0; h < 4; ++h) {
        float v = l[h] >= 0.f ? l[h] : NEG_SLOPE * l[h];
        op[h] = __expf(v);
    }
    *(float4*)&ex_csr[(size_t)i * 4] = o;
}

// ---------------------------------------------------------------------------
// Fused per-dst-node: softmax-weighted gather (CSR, precomputed ex) + bias
// + LayerNorm (+residual) + ELU -> h_out (bf16). 2 nodes/wave, 16B gathers.
// ---------------------------------------------------------------------------
__global__ __launch_bounds__(256) void aggregate_ln_elu(
    const int* __restrict__ rp, const int* __restrict__ csr_src,
    const float* __restrict__ ex_csr, const bf16* __restrict__ hs,
    const float* __restrict__ bias, const float* __restrict__ g,
    const float* __restrict__ b,
    const bf16* __restrict__ res, bf16* __restrict__ h_out, int n_dst)
{
    const int wvg  = (blockIdx.x * 256 + threadIdx.x) >> 6;  // global wave id
    const int lane = threadIdx.x & 63;
    const int half = lane >> 5;           // which node of the pair
    const int l32  = lane & 31;           // lane within node
    const int d    = wvg * 2 + half;
    if (wvg * 2 >= n_dst) return;
    const bool valid = d < n_dst;
    const int head = l32 >> 3;            // 8 lanes per head

    int beg = 0, end = 0;
    if (valid) { beg = rp[d]; end = rp[d + 1]; }

    float acc[8] = {};
    float den = 0.f;
    int i = beg;
    for (; i + 2 <= end; i += 2) {
        int s0 = csr_src[i], s1 = csr_src[i + 1];
        float e0 = ex_csr[(size_t)i * 4 + head];
        float e1 = ex_csr[(size_t)(i + 1) * 4 + head];
        short8 v0 = *(const short8*)&hs[(size_t)s0 * HDIM + l32 * 8];
        short8 v1 = *(const short8*)&hs[(size_t)s1 * HDIM + l32 * 8];
        den += e0 + e1;
#pragma unroll
        for (int j = 0; j < 8; ++j)
            acc[j] += e0 * b2f(v0[j]) + e1 * b2f(v1[j]);
    }
    if (i < end) {
        int s0 = csr_src[i];
        float e0 = ex_csr[(size_t)i * 4 + head];
        short8 v0 = *(const short8*)&hs[(size_t)s0 * HDIM + l32 * 8];
        den += e0;
#pragma unroll
        for (int j = 0; j < 8; ++j)
            acc[j] += e0 * b2f(v0[j]);
    }

    float inv = den > 0.f ? __builtin_amdgcn_rcpf(den) : 0.f;
    const float4* bp = (const float4*)(bias + l32 * 8);
    float4 bi0 = bp[0], bi1 = bp[1];
    float bb_[8] = {bi0.x, bi0.y, bi0.z, bi0.w, bi1.x, bi1.y, bi1.z, bi1.w};

    float x[8];
#pragma unroll
    for (int j = 0; j < 8; ++j) x[j] = acc[j] * inv + bb_[j];

    float s1 = ((x[0] + x[1]) + (x[2] + x[3])) + ((x[4] + x[5]) + (x[6] + x[7]));
    float s2 = 0.f;
#pragma unroll
    for (int j = 0; j < 8; ++j) s2 += x[j] * x[j];
#pragma unroll
    for (int off = 1; off < 32; off <<= 1) {
        s1 += __shfl_xor(s1, off);
        s2 += __shfl_xor(s2, off);
    }
    float mu = s1 * (1.f / 256.f);
    float var = s2 * (1.f / 256.f) - mu * mu;
    float rstd = rsqrtf(var + LN_EPS);

    const float4* gp = (const float4*)(g + l32 * 8);
    const float4* lbp = (const float4*)(b + l32 * 8);
    float4 g0 = gp[0], g1 = gp[1];
    float4 lb0 = lbp[0], lb1 = lbp[1];
    float gg_[8] = {g0.x, g0.y, g0.z, g0.w, g1.x, g1.y, g1.z, g1.w};
    float lb_[8] = {lb0.x, lb0.y, lb0.z, lb0.w, lb1.x, lb1.y, lb1.z, lb1.w};

    float y[8];
#pragma unroll
    for (int j = 0; j < 8; ++j)
        y[j] = (x[j] - mu) * rstd * gg_[j] + lb_[j];

    if (res && valid) {
        short8 r = *(const short8*)&res[(size_t)d * HDIM + l32 * 8];
#pragma unroll
        for (int j = 0; j < 8; ++j) y[j] += b2f(r[j]);
    }

    short8 o;
#pragma unroll
    for (int j = 0; j < 8; ++j) {
        float e = __expf(y[j]) - 1.f;        // fast ELU negative branch
        float v = y[j] > 0.f ? y[j] : e;
        o[j] = f2b(v);
    }
    if (valid)
        *(short8*)&h_out[(size_t)d * HDIM + l32 * 8] = o;
}

// ---------------------------------------------------------------------------
// Pool: mean over incoming at-edges of h_addr -> pooled (bf16). 2 nodes/wave.
// ---------------------------------------------------------------------------
__global__ __launch_bounds__(256) void k_pool(
    const int* __restrict__ rp, const int* __restrict__ csr_src,
    const bf16* __restrict__ h, bf16* __restrict__ out, int n_dst)
{
    const int wvg  = (blockIdx.x * 256 + threadIdx.x) >> 6;
    const int lane = threadIdx.x & 63;
    const int half = lane >> 5;
    const int l32  = lane & 31;
    const int d    = wvg * 2 + half;
    if (wvg * 2 >= n_dst) return;
    const bool valid = d < n_dst;

    int beg = 0, end = 0;
    if (valid) { beg = rp[d]; end = rp[d + 1]; }

    float acc[8] = {};
    int i = beg;
    for (; i + 2 <= end; i += 2) {
        int s0 = csr_src[i], s1 = csr_src[i + 1];
        short8 v0 = *(const short8*)&h[(size_t)s0 * HDIM + l32 * 8];
        short8 v1 = *(const short8*)&h[(size_t)s1 * HDIM + l32 * 8];
#pragma unroll
        for (int j = 0; j < 8; ++j)
            acc[j] += b2f(v0[j]) + b2f(v1[j]);
    }
    if (i < end) {
        short8 v0 = *(const short8*)&h[(size_t)csr_src[i] * HDIM + l32 * 8];
#pragma unroll
        for (int j = 0; j < 8; ++j) acc[j] += b2f(v0[j]);
    }
    int deg = end - beg;
    float c = deg > 0 ? __builtin_amdgcn_rcpf((float)deg) : 1.f;
    short8 o;
#pragma unroll
    for (int j = 0; j < 8; ++j) o[j] = f2b(acc[j] * c);
    if (valid)
        *(short8*)&out[(size_t)d * HDIM + l32 * 8] = o;
}

// ---------------------------------------------------------------------------
extern "C" void kernel_launch(void* const* d_in, const int* in_sizes, int n_in,
                              void* d_out, int out_size, void* d_ws, size_t ws_size,
                              hipStream_t stream)
{
    const float* x_tx      = (const float*)d_in[0];
    const float* x_addr    = (const float*)d_in[1];
    const int* addr_idx_at = (const int*)d_in[2];
    const int* tx_idx_at   = (const int*)d_in[3];
    const int* tx_idx_ta   = (const int*)d_in[4];
    const int* addr_idx_ta = (const int*)d_in[5];
    const float* w_in_tx   = (const float*)d_in[6];
    const float* b_in_tx   = (const float*)d_in[7];
    const float* w_in_addr = (const float*)d_in[8];
    const float* b_in_addr = (const float*)d_in[9];
    const float* w_at[2]  = {(const float*)d_in[10], (const float*)d_in[18]};
    const float* as_at[2] = {(const float*)d_in[11], (const float*)d_in[19]};
    const float* ad_at[2] = {(const float*)d_in[12], (const float*)d_in[20]};
    const float* b_at[2]  = {(const float*)d_in[13], (const float*)d_in[21]};
    const float* w_ta[2]  = {(const float*)d_in[14], (const float*)d_in[22]};
    const float* as_ta[2] = {(const float*)d_in[15], (const float*)d_in[23]};
    const float* ad_ta[2] = {(const float*)d_in[16], (const float*)d_in[24]};
    const float* b_ta[2]  = {(const float*)d_in[17], (const float*)d_in[25]};
    const float* ln_g_tx   = (const float*)d_in[26];
    const float* ln_b_tx   = (const float*)d_in[27];
    const float* ln_g_addr = (const float*)d_in[28];
    const float* ln_b_addr = (const float*)d_in[29];
    const float* w_out     = (const float*)d_in[30];
    const float* b_out     = (const float*)d_in[31];

    // ---- workspace carve-out (256B aligned) ----
    char* p = (char*)d_ws;
    auto alloc = [&](size_t bytes) -> void* {
        void* r = (void*)p; p += (bytes + 255) & ~(size_t)255; return r;
    };
    bf16* h0_tx   = (bf16*)alloc((size_t)NTX * 64 * 2);
    bf16* h0_addr = (bf16*)alloc((size_t)NADDR * 64 * 2);
    bf16* h_tx    = (bf16*)alloc((size_t)NTX * HDIM * 2);
    bf16* h_addr  = (bf16*)alloc((size_t)NADDR * HDIM * 2);
    bf16* hs_a    = (bf16*)alloc((size_t)NADDR * HDIM * 2);
    bf16* hs_t    = (bf16*)alloc((size_t)NTX * HDIM * 2);   // also pooled buffer
    float* al_src_at = (float*)alloc((size_t)NADDR * 4 * 4);
    float* al_dst_at = (float*)alloc((size_t)NTX * 4 * 4);
    float* al_src_ta = (float*)alloc((size_t)NTX * 4 * 4);
    float* al_dst_ta = (float*)alloc((size_t)NADDR * 4 * 4);
    float* Vd_at  = (float*)alloc(HDIM * 4 * 4);
    float* Vd_ta  = (float*)alloc(HDIM * 4 * 4);
    float* ex_csr = (float*)alloc((size_t)NEDGE * 4 * 4);
    int* rp_at    = (int*)alloc((size_t)(NTX + 1) * 4);
    int* rp_ta    = (int*)alloc((size_t)(NADDR + 1) * 4);
    int* csr_src_at = (int*)alloc((size_t)NEDGE * 4);
    int* csr_dst_at = (int*)alloc((size_t)NEDGE * 4);
    int* csr_src_ta = (int*)alloc((size_t)NEDGE * 4);
    int* csr_dst_ta = (int*)alloc((size_t)NEDGE * 4);
    int* deg_tx   = (int*)alloc((size_t)NTX * 4);
    int* deg_addr = (int*)alloc((size_t)NADDR * 4);
    int* cur_tx   = (int*)alloc((size_t)NTX * 4);
    int* cur_addr = (int*)alloc((size_t)NADDR * 4);
    int* bsum_tx  = (int*)alloc(1024 * 4);
    int* bsum_ad  = (int*)alloc(1024 * 4);
    // transposed bf16 weights: Wt[n][k]
    bf16* wt_at[2], *wt_ta[2], *wt_out, *wt_in_tx, *wt_in_addr;
    wt_at[0] = (bf16*)alloc((size_t)64 * HDIM * 2);
    wt_ta[0] = (bf16*)alloc((size_t)64 * HDIM * 2);
    wt_at[1] = (bf16*)alloc((size_t)HDIM * HDIM * 2);
    wt_ta[1] = (bf16*)alloc((size_t)HDIM * HDIM * 2);
    wt_out   = (bf16*)alloc((size_t)HDIM * HDIM * 2);
    wt_in_tx   = (bf16*)alloc((size_t)64 * FTXP * 2);
    wt_in_addr = (bf16*)alloc((size_t)64 * 64 * 2);
    // padded bf16 copies of the inputs. Alias h_tx/h_addr: those buffers are
    // first written by the layer-0 aggregates, long after the in-projections
    // consumed these (stream-ordered).
    bf16* xp_tx   = h_tx;     // [NTX][FTXP]   38.4 MB <= 51.2 MB
    bf16* xp_addr = h_addr;   // [NADDR][64]   25.6 MB <= 102.4 MB

    dim3 blk(256);
    const int EG = (NEDGE + 255) / 256;
    auto mfma_grid = [&](int M) { return dim3((M + 63) / 64); };
    auto mfma = [&](const bf16* A, const bf16* Wt, const float* bias, bf16* C,
                    int M, int K) {
        hipLaunchKernelGGL((gemm_mfma<bf16>), mfma_grid(M), blk, 0, stream,
                           A, Wt, bias, C, M, HDIM, K);
    };

    // ---- weight transpose+convert (tiny) ----
    hipLaunchKernelGGL(transpose_w_pad, dim3((64 * HDIM + 255) / 256), blk, 0, stream,
                       w_at[0], wt_at[0], 64, 64, HDIM);
    hipLaunchKernelGGL(transpose_w_pad, dim3((64 * HDIM + 255) / 256), blk, 0, stream,
                       w_ta[0], wt_ta[0], 64, 64, HDIM);
    hipLaunchKernelGGL(transpose_w_pad, dim3((HDIM * HDIM + 255) / 256), blk, 0, stream,
                       w_at[1], wt_at[1], HDIM, HDIM, HDIM);
    hipLaunchKernelGGL(transpose_w_pad, dim3((HDIM * HDIM + 255) / 256), blk, 0, stream,
                       w_ta[1], wt_ta[1], HDIM, HDIM, HDIM);
    hipLaunchKernelGGL(transpose_w_pad, dim3((HDIM * HDIM + 255) / 256), blk, 0, stream,
                       w_out, wt_out, HDIM, HDIM, HDIM);
    hipLaunchKernelGGL(transpose_w_pad, dim3((64 * FTXP + 255) / 256), blk, 0, stream,
                       w_in_tx, wt_in_tx, FTX, FTXP, 64);
    hipLaunchKernelGGL(transpose_w_pad, dim3((64 * 64 + 255) / 256), blk, 0, stream,
                       w_in_addr, wt_in_addr, 64, 64, 64);

    // ---- input convert (fp32 -> bf16, x_tx zero-padded to FTXP) ----
    hipLaunchKernelGGL(cvt_pad_bf16, dim3((NTX * (FTXP / 8) + 255) / 256), blk, 0,
                       stream, x_tx, xp_tx, NTX, FTX, FTXP);
    hipLaunchKernelGGL(cvt_pad_bf16, dim3((NADDR * (64 / 8) + 255) / 256), blk, 0,
                       stream, x_addr, xp_addr, NADDR, 64, 64);

    // ---- CSR build for both relations ----
    hipMemsetAsync(deg_tx, 0, (size_t)NTX * 4, stream);
    hipMemsetAsync(deg_addr, 0, (size_t)NADDR * 4, stream);
    hipMemsetAsync(cur_tx, 0, (size_t)NTX * 4, stream);
    hipMemsetAsync(cur_addr, 0, (size_t)NADDR * 4, stream);
    hipLaunchKernelGGL(k_hist, dim3(EG), blk, 0, stream, tx_idx_at, deg_tx, NEDGE);
    hipLaunchKernelGGL(k_hist, dim3(EG), blk, 0, stream, addr_idx_ta, deg_addr, NEDGE);
    const int NB_tx = (NTX + 1023) / 1024, NB_ad = (NADDR + 1023) / 1024;
    hipLaunchKernelGGL(scan_partial, dim3(NB_tx), blk, 0, stream, deg_tx, bsum_tx, NTX);
    hipLaunchKernelGGL(scan_partial, dim3(NB_ad), blk, 0, stream, deg_addr, bsum_ad, NADDR);
    hipLaunchKernelGGL(scan_bsum, dim3(1), blk, 0, stream, bsum_tx, NB_tx, rp_at, NTX, NEDGE);
    hipLaunchKernelGGL(scan_bsum, dim3(1), blk, 0, stream, bsum_ad, NB_ad, rp_ta, NADDR, NEDGE);
    hipLaunchKernelGGL(scan_write, dim3(NB_tx), blk, 0, stream, deg_tx, bsum_tx, rp_at, NTX);
    hipLaunchKernelGGL(scan_write, dim3(NB_ad), blk, 0, stream, deg_addr, bsum_ad, rp_ta, NADDR);
    hipLaunchKernelGGL(k_scatter, dim3(EG), blk, 0, stream,
                       addr_idx_at, tx_idx_at, rp_at, cur_tx, csr_src_at, csr_dst_at, NEDGE);
    hipLaunchKernelGGL(k_scatter, dim3(EG), blk, 0, stream,
                       tx_idx_ta, addr_idx_ta, rp_ta, cur_addr, csr_src_ta, csr_dst_ta, NEDGE);

    // ---- input projections (MFMA, N=64) ----
    hipLaunchKernelGGL(gemm_mfma64, mfma_grid(NTX), blk, 0, stream,
                       xp_tx, wt_in_tx, b_in_tx, h0_tx, NTX, FTXP);
    hipLaunchKernelGGL(gemm_mfma64, mfma_grid(NADDR), blk, 0, stream,
                       xp_addr, wt_in_addr, b_in_addr, h0_addr, NADDR, 64);

    for (int layer = 0; layer < 2; ++layer) {
        const int in_dim = layer ? HDIM : 64;
        const bf16* ftx = layer ? h_tx : h0_tx;
        const bf16* fad = layer ? h_addr : h0_addr;

        // projections for both relations (MFMA)
        mfma(fad, wt_at[layer], nullptr, hs_a, NADDR, in_dim);
        mfma(ftx, wt_ta[layer], nullptr, hs_t, NTX, in_dim);

        // attention logit halves
        hipLaunchKernelGGL(build_vd, dim3((in_dim * 4 + 255) / 256), blk, 0, stream,
                           w_at[layer], ad_at[layer], Vd_at, in_dim);
        hipLaunchKernelGGL(build_vd, dim3((in_dim * 4 + 255) / 256), blk, 0, stream,
                           w_ta[layer], ad_ta[layer], Vd_ta, in_dim);
        hipLaunchKernelGGL(attn_src, dim3((NADDR + 3) / 4), blk, 0, stream,
                           hs_a, as_at[layer], al_src_at, NADDR);
        hipLaunchKernelGGL(attn_src, dim3((NTX + 3) / 4), blk, 0, stream,
                           hs_t, as_ta[layer], al_src_ta, NTX);
        hipLaunchKernelGGL(attn_dst, dim3((NTX + 3) / 4), blk, 0, stream,
                           ftx, Vd_at, al_dst_at, NTX, in_dim);
        hipLaunchKernelGGL(attn_dst, dim3((NADDR + 3) / 4), blk, 0, stream,
                           fad, Vd_ta, al_dst_ta, NADDR, in_dim);

        // ---- relation at: aggregate into tx ----
        const bf16* res_tx = layer ? h_tx : nullptr;
        const bf16* res_ad = layer ? h_addr : nullptr;
        hipLaunchKernelGGL(edge_ex, dim3(EG), blk, 0, stream,
                           csr_src_at, csr_dst_at, al_src_at, al_dst_at, ex_csr, NEDGE);
        hipLaunchKernelGGL(aggregate_ln_elu, dim3((NTX + 7) / 8), blk, 0, stream,
                           rp_at, csr_src_at, ex_csr, hs_a,
                           b_at[layer], ln_g_tx, ln_b_tx, res_tx, h_tx, NTX);
        // ---- relation ta: aggregate into addr ----
        hipLaunchKernelGGL(edge_ex, dim3(EG), blk, 0, stream,
                           csr_src_ta, csr_dst_ta, al_src_ta, al_dst_ta, ex_csr, NEDGE);
        hipLaunchKernelGGL(aggregate_ln_elu, dim3((NADDR + 7) / 8), blk, 0, stream,
                           rp_ta, csr_src_ta, ex_csr, hs_t,
                           b_ta[layer], ln_g_addr, ln_b_addr, res_ad, h_addr, NADDR);
    }

    // ---- scatter-mean pooling (reuse at-CSR) + output projection (MFMA) ----
    hipLaunchKernelGGL(k_pool, dim3((NTX + 7) / 8), blk, 0, stream,
                       rp_at, csr_src_at, h_addr, hs_t, NTX);
    hipLaunchKernelGGL((gemm_mfma<float>), mfma_grid(NTX), blk, 0, stream,
                       hs_t, wt_out, b_out, (float*)d_out, NTX, HDIM, HDIM);
}